// Round 1
// baseline (652.636 us; speedup 1.0000x reference)
//
#include <hip/hip_runtime.h>
#include <hip/hip_bf16.h>

// MultiHeadAttention MI355X r1 baseline:
//   convert fp32->bf16, 3x QKV GEMM (m97-style, global_load_lds, split-head
//   epilogue), fused flash-attention (KVBLK=32, swizzled K LDS, transposed
//   swizzled V LDS, wave-parallel online softmax), output-projection GEMM.
// All bf16 MFMA 16x16x32, fp32 accum. B=2,S=2048,HID=2048,H=16,D=128.

typedef __attribute__((ext_vector_type(8))) short bf16x8;
typedef __attribute__((ext_vector_type(4))) float f32x4;
typedef unsigned short ushort_t;

#define MFMA_16x16x32(a, b, c) __builtin_amdgcn_mfma_f32_16x16x32_bf16((a), (b), (c), 0, 0, 0)

__device__ __forceinline__ ushort_t f2bf(float f) {
  unsigned int u = __builtin_bit_cast(unsigned int, f);
  u += 0x7fffu + ((u >> 16) & 1u);   // round-to-nearest-even
  return (ushort_t)(u >> 16);
}

// global -> LDS direct DMA, 16B/lane. LDS dest is wave-uniform base + lane*16.
__device__ __forceinline__ void gload_lds16(const void* g, void* lds) {
  __builtin_amdgcn_global_load_lds(
      (const __attribute__((address_space(1))) unsigned int*)g,
      (__attribute__((address_space(3))) unsigned int*)(unsigned int)(unsigned long long)lds,
      16, 0, 0);
}

// ---------------------------------------------------------------- converts
__global__ __launch_bounds__(256) void f2bf_kernel(const float* __restrict__ in,
                                                   ushort_t* __restrict__ out, int n4) {
  int i = blockIdx.x * blockDim.x + threadIdx.x;
  const int stride = gridDim.x * blockDim.x;
  for (; i < n4; i += stride) {
    const float4 v = ((const float4*)in)[i];
    ushort4 o;
    o.x = f2bf(v.x); o.y = f2bf(v.y); o.z = f2bf(v.z); o.w = f2bf(v.w);
    ((ushort4*)out)[i] = o;
  }
}

// ---------------------------------------------------------------- GEMM C = A @ B^T + bias
// A [M][K] bf16 row-major, B [N][K] bf16 row-major (nn.Linear weight layout).
// MODE 0: fp32 C[M][N] -> d_out.  MODE 1: bf16 split-head [B2][H][S][D2].
template <int MODE>
__global__ __launch_bounds__(256) void gemm_bt_kernel(const ushort_t* __restrict__ A,
                                                      const ushort_t* __restrict__ B,
                                                      const float* __restrict__ bias,
                                                      void* __restrict__ Cout,
                                                      int M, int N, int K) {
  __shared__ __align__(16) char smem[16384];
  char* sA = smem;           // [128][32] bf16, 8KB
  char* sB = smem + 8192;    // [128][32] bf16, 8KB
  const int tid = threadIdx.x;
  const int wave = tid >> 6;
  const int lane = tid & 63;
  const int wr = wave >> 1, wc = wave & 1;
  const int brow = blockIdx.y * 128;
  const int bcol = blockIdx.x * 128;

  const f32x4 fzero = {0.f, 0.f, 0.f, 0.f};
  f32x4 acc[4][4];
#pragma unroll
  for (int i = 0; i < 4; ++i)
#pragma unroll
    for (int j = 0; j < 4; ++j) acc[i][j] = fzero;

  const int srow = lane >> 2;        // row within 16-row chunk
  const int koff = (lane & 3) * 8;   // bf16 elems

  for (int kt = 0; kt < K; kt += 32) {
#pragma unroll
    for (int c = 0; c < 2; ++c) {
      const int ch = wave + c * 4;   // 8 chunks of 16 rows
      gload_lds16(A + (size_t)(brow + ch * 16 + srow) * K + kt + koff, sA + ch * 1024);
      gload_lds16(B + (size_t)(bcol + ch * 16 + srow) * K + kt + koff, sB + ch * 1024);
    }
    __syncthreads();   // vmcnt(0) drain + barrier
    bf16x8 af[4], bfr[4];
#pragma unroll
    for (int i = 0; i < 4; ++i)
      af[i] = *(const bf16x8*)(sA + (wr * 64 + i * 16 + (lane & 15)) * 64 + (lane >> 4) * 16);
#pragma unroll
    for (int j = 0; j < 4; ++j)
      bfr[j] = *(const bf16x8*)(sB + (wc * 64 + j * 16 + (lane & 15)) * 64 + (lane >> 4) * 16);
#pragma unroll
    for (int i = 0; i < 4; ++i)
#pragma unroll
      for (int j = 0; j < 4; ++j) acc[i][j] = MFMA_16x16x32(af[i], bfr[j], acc[i][j]);
    __syncthreads();
  }

#pragma unroll
  for (int i = 0; i < 4; ++i) {
#pragma unroll
    for (int j = 0; j < 4; ++j) {
#pragma unroll
      for (int r = 0; r < 4; ++r) {
        // verified C/D map: row = (lane>>4)*4 + r, col = lane&15 (m89)
        const int row = brow + wr * 64 + i * 16 + (lane >> 4) * 4 + r;
        const int col = bcol + wc * 64 + j * 16 + (lane & 15);
        const float v = acc[i][j][r] + bias[col];
        if (MODE == 0) {
          ((float*)Cout)[(size_t)row * N + col] = v;
        } else {
          // row -> (b, s); col -> (h, d); write [b][h][s][d] bf16
          const int b = row >> 11, s = row & 2047;
          const int h = col >> 7, d = col & 127;
          ((ushort_t*)Cout)[(((size_t)b * 16 + h) * 2048 + s) * 128 + d] = f2bf(v);
        }
      }
    }
  }
}

// ---------------------------------------------------------------- flash attention
// grid: 1024 = (B*H=32) x (S/64=32 q-tiles); 4 waves x 16 q-rows each.
__global__ __launch_bounds__(256) void attn_kernel(const ushort_t* __restrict__ Q,
                                                   const ushort_t* __restrict__ K,
                                                   const ushort_t* __restrict__ V,
                                                   ushort_t* __restrict__ O) {
  constexpr int S = 2048, D = 128, H = 16;
  __shared__ __align__(16) char smem[8192 + 10240 + 5120];
  char* sK = smem;            // [32][128] bf16, XOR-swizzled (byte ^= (row&7)<<4)
  char* sV = smem + 8192;     // transposed [128][40 shorts], chunk-XOR swizzled
  char* sP = smem + 18432;    // per-wave [16][40 shorts]

  const int tid = threadIdx.x;
  const int wave = tid >> 6;
  const int lane = tid & 63;
  const int qt = blockIdx.x & 31;
  const int bh = blockIdx.x >> 5;
  const int b = bh >> 4, h = bh & 15;

  const ushort_t* Qb = Q + (size_t)bh * S * D;
  const ushort_t* Kb = K + (size_t)bh * S * D;
  const ushort_t* Vb = V + (size_t)bh * S * D;
  const int q0 = qt * 64 + wave * 16;

  // Q fragments held in registers for the whole block (A-operand rows = lane&15)
  bf16x8 aq[4];
  {
    const ushort_t* qrow = Qb + (size_t)(q0 + (lane & 15)) * D + (lane >> 4) * 8;
#pragma unroll
    for (int kk = 0; kk < 4; ++kk) aq[kk] = *(const bf16x8*)(qrow + kk * 32);
  }

  const f32x4 fzero = {0.f, 0.f, 0.f, 0.f};
  f32x4 o[8];
#pragma unroll
  for (int nt = 0; nt < 8; ++nt) o[nt] = fzero;
  float row_m[4] = {-1e30f, -1e30f, -1e30f, -1e30f};
  float row_l[4] = {0.f, 0.f, 0.f, 0.f};

  char* sPw = sP + wave * 1280;
  const float scale = 0.08838834764831845f;  // 1/sqrt(128)
  const float LOG2E = 1.4426950408889634f;

  for (int kv0 = 0; kv0 < S; kv0 += 32) {
    __syncthreads();  // prior PV reads done before restage
    // ---- stage K [32][128] swizzled (16B vector writes)
#pragma unroll
    for (int c = 0; c < 2; ++c) {
      const int idx = c * 256 + tid;
      const int row = idx >> 4, ch = idx & 15;
      const int4 v = *(const int4*)(Kb + (size_t)(kv0 + row) * D + ch * 8);
      *(int4*)(sK + ((row * 256 + ch * 16) ^ ((row & 7) << 4))) = v;
    }
    // ---- stage V transposed [d][kv], stride 80B, chunk XOR ((d>>3)&3)
#pragma unroll
    for (int c = 0; c < 2; ++c) {
      const int idx = c * 256 + tid;
      const int kv = idx >> 4, ch = idx & 15;
      union { int4 q; ushort_t u[8]; } un;
      un.q = *(const int4*)(Vb + (size_t)(kv0 + kv) * D + ch * 8);
#pragma unroll
      for (int i = 0; i < 8; ++i) {
        const int d = ch * 8 + i;
        *(ushort_t*)(sV + d * 80 + (((kv >> 3) ^ ((d >> 3) & 3)) << 4) + (kv & 7) * 2) = un.u[i];
      }
    }
    __syncthreads();

    // ---- S = Q K^T  (two 16-col tiles of the 32 kv rows)
    f32x4 sfrag[2];
#pragma unroll
    for (int nt = 0; nt < 2; ++nt) {
      sfrag[nt] = fzero;
#pragma unroll
      for (int kk = 0; kk < 4; ++kk) {
        const int row = nt * 16 + (lane & 15);
        const bf16x8 bk = *(const bf16x8*)(sK + ((row * 256 + kk * 64 + (lane >> 4) * 16) ^ ((row & 7) << 4)));
        sfrag[nt] = MFMA_16x16x32(aq[kk], bk, sfrag[nt]);
      }
    }

    // ---- online softmax; lane group (lane>>4) holds q-rows q0+(lane>>4)*4+r
#pragma unroll
    for (int r = 0; r < 4; ++r) {
      const float s0 = sfrag[0][r] * scale;
      const float s1 = sfrag[1][r] * scale;
      float mx = fmaxf(s0, s1);
      mx = fmaxf(mx, __shfl_xor(mx, 1));
      mx = fmaxf(mx, __shfl_xor(mx, 2));
      mx = fmaxf(mx, __shfl_xor(mx, 4));
      mx = fmaxf(mx, __shfl_xor(mx, 8));
      const float nm = fmaxf(row_m[r], mx);
      const float corr = exp2f((row_m[r] - nm) * LOG2E);
      row_m[r] = nm;
      const float p0 = exp2f((s0 - nm) * LOG2E);
      const float p1 = exp2f((s1 - nm) * LOG2E);
      float rs = p0 + p1;
      rs += __shfl_xor(rs, 1);
      rs += __shfl_xor(rs, 2);
      rs += __shfl_xor(rs, 4);
      rs += __shfl_xor(rs, 8);
      row_l[r] = row_l[r] * corr + rs;
#pragma unroll
      for (int nt = 0; nt < 8; ++nt) o[nt][r] *= corr;
      const int prow = (lane >> 4) * 4 + r;
      *(ushort_t*)(sPw + prow * 80 + (lane & 15) * 2) = f2bf(p0);
      *(ushort_t*)(sPw + prow * 80 + ((lane & 15) + 16) * 2) = f2bf(p1);
    }
    __syncthreads();  // P visible (+ wave LDS ordering)

    // ---- O += P V   (A = P[16][32] from LDS, B = V via transposed tile)
    const bf16x8 pa = *(const bf16x8*)(sPw + (lane & 15) * 80 + (lane >> 4) * 16);
#pragma unroll
    for (int nt = 0; nt < 8; ++nt) {
      const int d = nt * 16 + (lane & 15);
      const bf16x8 bv = *(const bf16x8*)(sV + d * 80 + (((lane >> 4) ^ ((d >> 3) & 3)) << 4));
      o[nt] = MFMA_16x16x32(pa, bv, o[nt]);
    }
  }

  // ---- epilogue: O/l -> bf16 [B*S][H*D] (concat-head, A-input of out-proj)
#pragma unroll
  for (int r = 0; r < 4; ++r) {
    const float inv = 1.0f / row_l[r];
    const int srow = q0 + (lane >> 4) * 4 + r;
    ushort_t* orow = O + ((size_t)b * S + srow) * (H * D) + h * D;
#pragma unroll
    for (int nt = 0; nt < 8; ++nt) orow[nt * 16 + (lane & 15)] = f2bf(o[nt][r] * inv);
  }
}

// ---------------------------------------------------------------- launch
extern "C" void kernel_launch(void* const* d_in, const int* in_sizes, int n_in,
                              void* d_out, int out_size, void* d_ws, size_t ws_size,
                              hipStream_t stream) {
  const float* hidden = (const float*)d_in[0];
  const float* Wq = (const float*)d_in[1];
  const float* bq = (const float*)d_in[2];
  const float* Wk = (const float*)d_in[3];
  const float* bk = (const float*)d_in[4];
  const float* Wv = (const float*)d_in[5];
  const float* bv = (const float*)d_in[6];
  const float* Wo = (const float*)d_in[7];
  const float* bo = (const float*)d_in[8];

  constexpr int M = 4096, N = 2048, Kd = 2048;  // M = B*S
  char* ws = (char*)d_ws;
  // ws layout (bytes): hb 16M | wq/wk/wv/wo 8M each | Q/K/V 16M each | AO 16M  = 112MB
  ushort_t* hb  = (ushort_t*)(ws);
  ushort_t* wqb = (ushort_t*)(ws + (16u << 20));
  ushort_t* wkb = (ushort_t*)(ws + (16u << 20) + 1u * (8u << 20));
  ushort_t* wvb = (ushort_t*)(ws + (16u << 20) + 2u * (8u << 20));
  ushort_t* wob = (ushort_t*)(ws + (16u << 20) + 3u * (8u << 20));
  ushort_t* Qs  = (ushort_t*)(ws + (16u << 20) + 4u * (8u << 20));
  ushort_t* Ks  = Qs + (size_t)M * N;
  ushort_t* Vs  = Ks + (size_t)M * N;
  ushort_t* AO  = Vs + (size_t)M * N;

  f2bf_kernel<<<2048, 256, 0, stream>>>(hidden, hb, M * Kd / 4);
  f2bf_kernel<<<1024, 256, 0, stream>>>(Wq, wqb, N * Kd / 4);
  f2bf_kernel<<<1024, 256, 0, stream>>>(Wk, wkb, N * Kd / 4);
  f2bf_kernel<<<1024, 256, 0, stream>>>(Wv, wvb, N * Kd / 4);
  f2bf_kernel<<<1024, 256, 0, stream>>>(Wo, wob, N * Kd / 4);

  dim3 gg(N / 128, M / 128);  // 16 x 32 tiles
  gemm_bt_kernel<1><<<gg, 256, 0, stream>>>(hb, wqb, bq, Qs, M, N, Kd);
  gemm_bt_kernel<1><<<gg, 256, 0, stream>>>(hb, wkb, bk, Ks, M, N, Kd);
  gemm_bt_kernel<1><<<gg, 256, 0, stream>>>(hb, wvb, bv, Vs, M, N, Kd);
  attn_kernel<<<1024, 256, 0, stream>>>(Qs, Ks, Vs, AO);
  gemm_bt_kernel<0><<<gg, 256, 0, stream>>>(AO, wob, bo, d_out, M, N, Kd);
}

// Round 3
// 571.911 us; speedup vs baseline: 1.1411x; 1.1411x over previous
//
#include <hip/hip_runtime.h>
#include <hip/hip_bf16.h>

// MultiHeadAttention MI355X r2 (resubmit r3 — r2 bench lost to GPU broker timeout):
//   R1 post-mortem: attn = 314us of 652, MfmaUtil 9%, 4.3e7 bank conflicts
//   from scalar V-transpose staging (16-way store conflicts) + KVBLK=32
//   softmax/barrier overhead.
//   R2 changes (attention only; GEMM structure untouched for clean A/B):
//   - V^T computed at the source: V^T = Wv @ H^T via gemm_bt(A=Wv, B=H),
//     MODE 2 epilogue writes [b][h][d][s]. No in-kernel transpose.
//   - K and V^T staged with global_load_lds (16B/lane), LDS linear dest +
//     pre-swizzled per-lane global source (involution byte^=((row&7)<<4)).
//   - KVBLK 64 (half the barriers/softmax passes per kv row).
//   - P tile wave-private (no 3rd barrier), row stride 144B (pa-read 2-way).
//   - T13 defer-max (THR=8): skip O-rescale while tile max stays in band.
// All bf16 MFMA 16x16x32, fp32 accum. B=2,S=2048,HID=2048,H=16,D=128.

typedef __attribute__((ext_vector_type(8))) short bf16x8;
typedef __attribute__((ext_vector_type(4))) float f32x4;
typedef unsigned short ushort_t;

#define MFMA_16x16x32(a, b, c) __builtin_amdgcn_mfma_f32_16x16x32_bf16((a), (b), (c), 0, 0, 0)

__device__ __forceinline__ ushort_t f2bf(float f) {
  unsigned int u = __builtin_bit_cast(unsigned int, f);
  u += 0x7fffu + ((u >> 16) & 1u);   // round-to-nearest-even
  return (ushort_t)(u >> 16);
}

// global -> LDS direct DMA, 16B/lane. LDS dest = wave-uniform base + lane*16;
// global src is per-lane (pre-swizzle it to realize swizzled LDS layouts).
__device__ __forceinline__ void gload_lds16(const void* g, void* lds) {
  __builtin_amdgcn_global_load_lds(
      (const __attribute__((address_space(1))) unsigned int*)g,
      (__attribute__((address_space(3))) unsigned int*)(unsigned int)(unsigned long long)lds,
      16, 0, 0);
}

// ---------------------------------------------------------------- converts
__global__ __launch_bounds__(256) void f2bf_kernel(const float* __restrict__ in,
                                                   ushort_t* __restrict__ out, int n4) {
  int i = blockIdx.x * blockDim.x + threadIdx.x;
  const int stride = gridDim.x * blockDim.x;
  for (; i < n4; i += stride) {
    const float4 v = ((const float4*)in)[i];
    ushort4 o;
    o.x = f2bf(v.x); o.y = f2bf(v.y); o.z = f2bf(v.z); o.w = f2bf(v.w);
    ((ushort4*)out)[i] = o;
  }
}

// ---------------------------------------------------------------- GEMM C = A @ B^T + bias
// A [M][K] bf16 row-major, B [N][K] bf16 row-major.
// MODE 0: fp32 C[M][N] -> d_out, bias[col].
// MODE 1: bf16 split-head [b][h][s][d]; row=(b,s), col=(h,d), bias[col].
// MODE 2: bf16 transposed split-head [b][h][d][s]; A=weight so row=(h,d),
//         B=hidden so col=(b,s), bias[row].  (C = Wv H^T = V^T)
template <int MODE>
__global__ __launch_bounds__(256) void gemm_bt_kernel(const ushort_t* __restrict__ A,
                                                      const ushort_t* __restrict__ B,
                                                      const float* __restrict__ bias,
                                                      void* __restrict__ Cout,
                                                      int M, int N, int K) {
  __shared__ __align__(16) char smem[16384];
  char* sA = smem;           // [128][32] bf16, 8KB
  char* sB = smem + 8192;    // [128][32] bf16, 8KB
  const int tid = threadIdx.x;
  const int wave = tid >> 6;
  const int lane = tid & 63;
  const int wr = wave >> 1, wc = wave & 1;
  const int brow = blockIdx.y * 128;
  const int bcol = blockIdx.x * 128;

  const f32x4 fzero = {0.f, 0.f, 0.f, 0.f};
  f32x4 acc[4][4];
#pragma unroll
  for (int i = 0; i < 4; ++i)
#pragma unroll
    for (int j = 0; j < 4; ++j) acc[i][j] = fzero;

  const int srow = lane >> 2;        // row within 16-row chunk
  const int koff = (lane & 3) * 8;   // bf16 elems

  for (int kt = 0; kt < K; kt += 32) {
#pragma unroll
    for (int c = 0; c < 2; ++c) {
      const int ch = wave + c * 4;   // 8 chunks of 16 rows
      gload_lds16(A + (size_t)(brow + ch * 16 + srow) * K + kt + koff, sA + ch * 1024);
      gload_lds16(B + (size_t)(bcol + ch * 16 + srow) * K + kt + koff, sB + ch * 1024);
    }
    __syncthreads();   // vmcnt(0) drain + barrier
    bf16x8 af[4], bfr[4];
#pragma unroll
    for (int i = 0; i < 4; ++i)
      af[i] = *(const bf16x8*)(sA + (wr * 64 + i * 16 + (lane & 15)) * 64 + (lane >> 4) * 16);
#pragma unroll
    for (int j = 0; j < 4; ++j)
      bfr[j] = *(const bf16x8*)(sB + (wc * 64 + j * 16 + (lane & 15)) * 64 + (lane >> 4) * 16);
#pragma unroll
    for (int i = 0; i < 4; ++i)
#pragma unroll
      for (int j = 0; j < 4; ++j) acc[i][j] = MFMA_16x16x32(af[i], bfr[j], acc[i][j]);
    __syncthreads();
  }

#pragma unroll
  for (int i = 0; i < 4; ++i) {
#pragma unroll
    for (int j = 0; j < 4; ++j) {
#pragma unroll
      for (int r = 0; r < 4; ++r) {
        // verified C/D map: row = (lane>>4)*4 + r, col = lane&15 (m89)
        const int row = brow + wr * 64 + i * 16 + (lane >> 4) * 4 + r;
        const int col = bcol + wc * 64 + j * 16 + (lane & 15);
        const float v = acc[i][j][r] + ((MODE == 2) ? bias[row] : bias[col]);
        if (MODE == 0) {
          ((float*)Cout)[(size_t)row * N + col] = v;
        } else if (MODE == 1) {
          const int b = row >> 11, s = row & 2047;
          const int h = col >> 7, d = col & 127;
          ((ushort_t*)Cout)[(((size_t)b * 16 + h) * 2048 + s) * 128 + d] = f2bf(v);
        } else {
          const int h = row >> 7, d = row & 127;
          const int b = col >> 11, s = col & 2047;
          ((ushort_t*)Cout)[(((size_t)b * 16 + h) * 128 + d) * 2048 + s] = f2bf(v);
        }
      }
    }
  }
}

// ---------------------------------------------------------------- flash attention
// grid: 1024 = (B*H=32) x (S/64=32 q-tiles); 4 waves x 16 q-rows; KVBLK=64.
// K [b][h][s][d]; Vt [b][h][d][s] (pre-transposed by MODE-2 GEMM).
__global__ __launch_bounds__(256) void attn_kernel(const ushort_t* __restrict__ Q,
                                                   const ushort_t* __restrict__ K,
                                                   const ushort_t* __restrict__ Vt,
                                                   ushort_t* __restrict__ O) {
  constexpr int S = 2048, D = 128, H = 16;
  __shared__ __align__(16) char smem[16384 + 16384 + 9216];
  char* sK = smem;              // [64][128] bf16, phys = log ^ ((row&7)<<4), row=byte>>8
  char* sVt = smem + 16384;     // [128][64] bf16, phys = log ^ ((row&7)<<4), row=byte>>7
  char* sP = smem + 32768;      // per-wave [16 q][64 k] bf16, row stride 144B

  const int tid = threadIdx.x;
  const int wave = tid >> 6;
  const int lane = tid & 63;
  const int g = lane >> 4;      // 16-lane group
  const int l15 = lane & 15;
  const int qt = blockIdx.x & 31;
  const int bh = blockIdx.x >> 5;
  const int b = bh >> 4, h = bh & 15;

  const ushort_t* Qb = Q + (size_t)bh * S * D;
  const char* Kb = (const char*)(K + (size_t)bh * S * D);
  const char* Vtb = (const char*)(Vt + (size_t)bh * D * S);
  const int q0 = qt * 64 + wave * 16;

  // Q fragments in registers for the whole block (A rows = lane&15)
  bf16x8 aq[4];
  {
    const ushort_t* qrow = Qb + (size_t)(q0 + l15) * D + g * 8;
#pragma unroll
    for (int kk = 0; kk < 4; ++kk) aq[kk] = *(const bf16x8*)(qrow + kk * 32);
  }

  // Pre-swizzled per-lane global sources for linear-dest global_load_lds.
  // Physical LDS chunk p holds data of logical chunk p ^ ((row(p)&7)<<4).
  const char* kg[4];
  const char* vg[4];
#pragma unroll
  for (int i = 0; i < 4; ++i) {
    const int po = (wave * 4 + i) * 1024 + lane * 16;
    const int lk = po ^ (((po >> 8) & 7) << 4);   // K tile: 64 rows x 256B
    kg[i] = Kb + (size_t)(lk >> 8) * 256 + (lk & 255);
    const int lv = po ^ (((po >> 7) & 7) << 4);   // Vt tile: 128 rows x 128B
    vg[i] = Vtb + (size_t)(lv >> 7) * 4096 + (lv & 127);
  }

  const f32x4 fzero = {0.f, 0.f, 0.f, 0.f};
  f32x4 o[8];
#pragma unroll
  for (int nt = 0; nt < 8; ++nt) o[nt] = fzero;
  float row_m[4] = {-1e30f, -1e30f, -1e30f, -1e30f};
  float row_l[4] = {0.f, 0.f, 0.f, 0.f};

  char* sPw = sP + wave * 2304;
  const float scale = 0.08838834764831845f;  // 1/sqrt(128)
  const float LOG2E = 1.4426950408889634f;

  for (int kv0 = 0; kv0 < S; kv0 += 64) {
    __syncthreads();   // prior iter's sK/sVt reads done before restage
#pragma unroll
    for (int i = 0; i < 4; ++i)
      gload_lds16(kg[i] + (size_t)kv0 * 256, sK + (wave * 4 + i) * 1024);
#pragma unroll
    for (int i = 0; i < 4; ++i)
      gload_lds16(vg[i] + (size_t)kv0 * 2, sVt + (wave * 4 + i) * 1024);
    __syncthreads();   // vmcnt(0) drain: tiles ready

    // ---- S = Q K^T : 4 x (16 kv-cols) tiles
    f32x4 sfrag[4];
#pragma unroll
    for (int nt = 0; nt < 4; ++nt) {
      sfrag[nt] = fzero;
#pragma unroll
      for (int kk = 0; kk < 4; ++kk) {
        const int row = nt * 16 + l15;
        const int la = row * 256 + kk * 64 + g * 16;
        const bf16x8 bk = *(const bf16x8*)(sK + (la ^ ((row & 7) << 4)));
        sfrag[nt] = MFMA_16x16x32(aq[kk], bk, sfrag[nt]);
      }
    }

    // ---- online softmax (defer-max THR=8); lane holds S[q=g*4+r][kv=nt*16+l15]
#pragma unroll
    for (int r = 0; r < 4; ++r) {
      const float s0 = sfrag[0][r] * scale;
      const float s1 = sfrag[1][r] * scale;
      const float s2 = sfrag[2][r] * scale;
      const float s3 = sfrag[3][r] * scale;
      float mx = fmaxf(fmaxf(s0, s1), fmaxf(s2, s3));
      mx = fmaxf(mx, __shfl_xor(mx, 1));
      mx = fmaxf(mx, __shfl_xor(mx, 2));
      mx = fmaxf(mx, __shfl_xor(mx, 4));
      mx = fmaxf(mx, __shfl_xor(mx, 8));
      if (!__all(mx - row_m[r] <= 8.0f)) {   // wave-uniform branch
        const float nm = fmaxf(row_m[r], mx);
        const float corr = exp2f((row_m[r] - nm) * LOG2E);
        row_l[r] *= corr;
#pragma unroll
        for (int nt = 0; nt < 8; ++nt) o[nt][r] *= corr;
        row_m[r] = nm;
      }
      const float nm = row_m[r];
      const float p0 = exp2f((s0 - nm) * LOG2E);
      const float p1 = exp2f((s1 - nm) * LOG2E);
      const float p2 = exp2f((s2 - nm) * LOG2E);
      const float p3 = exp2f((s3 - nm) * LOG2E);
      float rs = (p0 + p1) + (p2 + p3);
      rs += __shfl_xor(rs, 1);
      rs += __shfl_xor(rs, 2);
      rs += __shfl_xor(rs, 4);
      rs += __shfl_xor(rs, 8);
      row_l[r] += rs;
      ushort_t* pr = (ushort_t*)(sPw + (g * 4 + r) * 144);
      pr[l15] = f2bf(p0);
      pr[16 + l15] = f2bf(p1);
      pr[32 + l15] = f2bf(p2);
      pr[48 + l15] = f2bf(p3);
    }

    // ---- O += P V  (sPw wave-private: no barrier, compiler orders via lgkmcnt)
    const bf16x8 pa0 = *(const bf16x8*)(sPw + l15 * 144 + g * 16);
    const bf16x8 pa1 = *(const bf16x8*)(sPw + l15 * 144 + 64 + g * 16);
#pragma unroll
    for (int nt = 0; nt < 8; ++nt) {
      const int d = nt * 16 + l15;
      const int la0 = d * 128 + g * 16;
      const bf16x8 bv0 = *(const bf16x8*)(sVt + (la0 ^ ((d & 7) << 4)));
      o[nt] = MFMA_16x16x32(pa0, bv0, o[nt]);
      const bf16x8 bv1 = *(const bf16x8*)(sVt + ((la0 + 64) ^ ((d & 7) << 4)));
      o[nt] = MFMA_16x16x32(pa1, bv1, o[nt]);
    }
  }

  // ---- epilogue: O/l -> bf16 [B*S][H*D] (A-input of out-proj)
#pragma unroll
  for (int r = 0; r < 4; ++r) {
    const float inv = 1.0f / row_l[r];
    const int srow = q0 + g * 4 + r;
    ushort_t* orow = O + ((size_t)b * S + srow) * (H * D) + h * D;
#pragma unroll
    for (int nt = 0; nt < 8; ++nt) orow[nt * 16 + l15] = f2bf(o[nt][r] * inv);
  }
}

// ---------------------------------------------------------------- launch
extern "C" void kernel_launch(void* const* d_in, const int* in_sizes, int n_in,
                              void* d_out, int out_size, void* d_ws, size_t ws_size,
                              hipStream_t stream) {
  const float* hidden = (const float*)d_in[0];
  const float* Wq = (const float*)d_in[1];
  const float* bq = (const float*)d_in[2];
  const float* Wk = (const float*)d_in[3];
  const float* bk = (const float*)d_in[4];
  const float* Wv = (const float*)d_in[5];
  const float* bv = (const float*)d_in[6];
  const float* Wo = (const float*)d_in[7];
  const float* bo = (const float*)d_in[8];

  constexpr int M = 4096, N = 2048, Kd = 2048;  // M = B*S
  char* ws = (char*)d_ws;
  // ws layout: hb 16M | wq/wk/wv/wo 8M each | Q 16M | K 16M | Vt 16M | AO 16M
  ushort_t* hb  = (ushort_t*)(ws);
  ushort_t* wqb = (ushort_t*)(ws + (16u << 20));
  ushort_t* wkb = (ushort_t*)(ws + (16u << 20) + 1u * (8u << 20));
  ushort_t* wvb = (ushort_t*)(ws + (16u << 20) + 2u * (8u << 20));
  ushort_t* wob = (ushort_t*)(ws + (16u << 20) + 3u * (8u << 20));
  ushort_t* Qs  = (ushort_t*)(ws + (16u << 20) + 4u * (8u << 20));
  ushort_t* Ks  = Qs + (size_t)M * N;
  ushort_t* Vts = Ks + (size_t)M * N;
  ushort_t* AO  = Vts + (size_t)M * N;

  f2bf_kernel<<<2048, 256, 0, stream>>>(hidden, hb, M * Kd / 4);
  f2bf_kernel<<<1024, 256, 0, stream>>>(Wq, wqb, N * Kd / 4);
  f2bf_kernel<<<1024, 256, 0, stream>>>(Wk, wkb, N * Kd / 4);
  f2bf_kernel<<<1024, 256, 0, stream>>>(Wv, wvb, N * Kd / 4);
  f2bf_kernel<<<1024, 256, 0, stream>>>(Wo, wob, N * Kd / 4);

  dim3 gg(N / 128, M / 128);    // 16 x 32 tiles
  gemm_bt_kernel<1><<<gg, 256, 0, stream>>>(hb, wqb, bq, Qs, M, N, Kd);
  gemm_bt_kernel<1><<<gg, 256, 0, stream>>>(hb, wkb, bk, Ks, M, N, Kd);
  dim3 ggv(M / 128, N / 128);   // V^T = Wv @ H^T: C is [2048][4096]
  gemm_bt_kernel<2><<<ggv, 256, 0, stream>>>(wvb, hb, bv, Vts, N, M, Kd);
  attn_kernel<<<1024, 256, 0, stream>>>(Qs, Ks, Vts, AO);
  gemm_bt_kernel<0><<<gg, 256, 0, stream>>>(AO, wob, bo, d_out, M, N, Kd);
}

// Round 4
// 559.583 us; speedup vs baseline: 1.1663x; 1.0220x over previous
//
#include <hip/hip_runtime.h>
#include <hip/hip_bf16.h>

// MultiHeadAttention MI355X r4:
//   R3 post-mortem: attn 224us (VALU-bound, conflicts now minor), 4 GEMMs ~300us
//   at ~460 TF (m97-structure shape ceiling). This round: GEMM subsystem only.
//   - qkv_fused_kernel: ONE 256x256xBK=32 GEMM over B=[Wq;Wk;Wv] (N=6144,
//     384 blocks, 512 thr / 8 waves 2Mx4N), TRIPLE-buffered LDS (96KB dynamic),
//     counted-vmcnt pipeline: stage kt+2 during kt, one vmcnt(4)+lgkmcnt(0)
//     +s_barrier gate per K-tile (T3/T4), setprio around MFMA (T5),
//     XOR-swizzled LDS reads via pre-swizzled global_load_lds sources
//     (involution slot^=(row>>1)&3, verified pattern from R3 attn),
//     bijective XCD swizzle (T1). Epilogue fans out Q/K (split-head) and
//     V^T (transposed split-head) per block column segment.
//   - out-proj kept on the old 128^2 kernel (internal control), attn unchanged.
// All bf16 MFMA 16x16x32, fp32 accum. B=2,S=2048,HID=2048,H=16,D=128.

typedef __attribute__((ext_vector_type(8))) short bf16x8;
typedef __attribute__((ext_vector_type(4))) float f32x4;
typedef unsigned short ushort_t;

#define MFMA_16x16x32(a, b, c) __builtin_amdgcn_mfma_f32_16x16x32_bf16((a), (b), (c), 0, 0, 0)

__device__ __forceinline__ ushort_t f2bf(float f) {
  unsigned int u = __builtin_bit_cast(unsigned int, f);
  u += 0x7fffu + ((u >> 16) & 1u);   // round-to-nearest-even
  return (ushort_t)(u >> 16);
}

// global -> LDS direct DMA, 16B/lane. LDS dest = wave-uniform base + lane*16;
// global src is per-lane (pre-swizzle it to realize swizzled LDS layouts).
__device__ __forceinline__ void gload_lds16(const void* g, void* lds) {
  __builtin_amdgcn_global_load_lds(
      (const __attribute__((address_space(1))) unsigned int*)g,
      (__attribute__((address_space(3))) unsigned int*)(unsigned int)(unsigned long long)lds,
      16, 0, 0);
}

// ---------------------------------------------------------------- converts
__global__ __launch_bounds__(256) void f2bf_kernel(const float* __restrict__ in,
                                                   ushort_t* __restrict__ out, int n4) {
  int i = blockIdx.x * blockDim.x + threadIdx.x;
  const int stride = gridDim.x * blockDim.x;
  for (; i < n4; i += stride) {
    const float4 v = ((const float4*)in)[i];
    ushort4 o;
    o.x = f2bf(v.x); o.y = f2bf(v.y); o.z = f2bf(v.z); o.w = f2bf(v.w);
    ((ushort4*)out)[i] = o;
  }
}

// ---------------------------------------------------------------- fused QKV GEMM
// C = A @ W^T + bias over W=[Wq;Wk;Wv] (6144x2048). BM=BN=256, BK=32.
// 512 threads = 8 waves (2M x 4N); per-wave 128x64; acc[8][4] f32x4.
// LDS: 3 buffers x (A 16KB + B 16KB) = 96KB dynamic.
// LDS swizzle: 16B-slot s_phys = s_log ^ ((row>>1)&3)  (conflict-free b128
// reads at 64B row stride; involution, applied on BOTH stage-src and read).
__global__ __launch_bounds__(512) void qkv_fused_kernel(
    const ushort_t* __restrict__ A,    // hidden bf16 [4096][2048]
    const ushort_t* __restrict__ W,    // [6144][2048]
    const float* __restrict__ bq, const float* __restrict__ bk,
    const float* __restrict__ bv,
    ushort_t* __restrict__ Qs, ushort_t* __restrict__ Ks,
    ushort_t* __restrict__ Vts) {
  constexpr int K = 2048, NT = K / 32;   // 64 K-tiles
  extern __shared__ char sm[];
  const int tid = threadIdx.x;
  const int wave = tid >> 6, lane = tid & 63;
  const int g = lane >> 4, l15 = lane & 15;
  const int wr = wave >> 2, wc = wave & 3;

  // T1: bijective XCD swizzle (384 % 8 == 0 -> 48 contiguous per XCD).
  // Within a chunk, consecutive s share 'by' -> A-panel reuse in XCD L2.
  const int bid = blockIdx.x;
  const int sw = (bid & 7) * 48 + (bid >> 3);
  const int bx = sw % 24, by = sw / 24;
  const int brow = by * 256, bcol = bx * 256;

  // Per-lane pre-swizzled staging sources (2 A-issues + 2 B-issues / wave / K-tile).
  // Linear dest slot p=(wave*2+j)*64+lane holds logical slot p^((row>>1)&3).
  const ushort_t* srcA[2];
  const ushort_t* srcB[2];
#pragma unroll
  for (int j = 0; j < 2; ++j) {
    const int p = (wave * 2 + j) * 64 + lane;
    const int row = p >> 2;
    const int col = (p & 3) ^ ((row >> 1) & 3);
    srcA[j] = A + (size_t)(brow + row) * K + col * 8;
    srcB[j] = W + (size_t)(bcol + row) * K + col * 8;
  }

  // Per-lane ds_read byte offsets (within a buffer). f(row)=(row>>1)&3==(l15>>1)&3.
  const int fph = (l15 >> 1) & 3;
  const int aOff = (wr * 128 + l15) * 64 + ((g ^ fph) << 4);
  const int bOff = (wc * 64 + l15) * 64 + ((g ^ fph) << 4) + 16384;

  char* p0 = sm;            // current K-tile
  char* p1 = sm + 32768;    // next
  char* p2 = sm + 65536;    // staging target (kt+2)

#define STAGE_A(P, t)                                                        \
  {                                                                          \
    gload_lds16(srcA[0] + (t) * 32, (P) + (wave * 2 + 0) * 1024);            \
    gload_lds16(srcA[1] + (t) * 32, (P) + (wave * 2 + 1) * 1024);            \
  }
#define STAGE_B(P, t)                                                        \
  {                                                                          \
    gload_lds16(srcB[0] + (t) * 32, (P) + 16384 + (wave * 2 + 0) * 1024);    \
    gload_lds16(srcB[1] + (t) * 32, (P) + 16384 + (wave * 2 + 1) * 1024);    \
  }

  const f32x4 fzero = {0.f, 0.f, 0.f, 0.f};
  f32x4 acc[8][4];
#pragma unroll
  for (int i = 0; i < 8; ++i)
#pragma unroll
    for (int j = 0; j < 4; ++j) acc[i][j] = fzero;

  // Prologue: stage kt0 -> p0, kt1 -> p1 (8 per-wave loads); retire kt0.
  STAGE_A(p0, 0); STAGE_B(p0, 0);
  STAGE_A(p1, 1); STAGE_B(p1, 1);
  asm volatile("s_waitcnt vmcnt(4)" ::: "memory");
  __builtin_amdgcn_sched_barrier(0);
  __builtin_amdgcn_s_barrier();
  __builtin_amdgcn_sched_barrier(0);

  // Ledger (per wave): entering iter kt, outstanding = kt+1's 4 loads.
  // Iter kt stages kt+2 (+4); gate vmcnt(4) retires exactly kt+1's loads.
  // Tail (kt >= NT-2): nothing staged; gate drains (vmcnt(0)) once.
  for (int kt = 0; kt < NT; ++kt) {
    const bool doStage = (kt < NT - 2);
    // ---- phase 1: stage A of kt+2; compute M-quarters 0..3
    if (doStage) STAGE_A(p2, kt + 2);
    bf16x8 bfr[4], afr[4];
#pragma unroll
    for (int j = 0; j < 4; ++j) bfr[j] = *(const bf16x8*)(p0 + bOff + j * 1024);
#pragma unroll
    for (int i = 0; i < 4; ++i) afr[i] = *(const bf16x8*)(p0 + aOff + i * 1024);
    __builtin_amdgcn_s_setprio(1);
#pragma unroll
    for (int i = 0; i < 4; ++i)
#pragma unroll
      for (int j = 0; j < 4; ++j) acc[i][j] = MFMA_16x16x32(afr[i], bfr[j], acc[i][j]);
    __builtin_amdgcn_s_setprio(0);
    // ---- phase 2: stage B of kt+2; compute M-quarters 4..7
    if (doStage) STAGE_B(p2, kt + 2);
#pragma unroll
    for (int i = 0; i < 4; ++i) afr[i] = *(const bf16x8*)(p0 + aOff + (4 + i) * 1024);
    __builtin_amdgcn_s_setprio(1);
#pragma unroll
    for (int i = 0; i < 4; ++i)
#pragma unroll
      for (int j = 0; j < 4; ++j) acc[4 + i][j] = MFMA_16x16x32(afr[i], bfr[j], acc[4 + i][j]);
    __builtin_amdgcn_s_setprio(0);
    // ---- gate: kt+1 ready for all waves; lgkmcnt(0) so no in-flight ds_read
    // of p0 survives the barrier (next iters re-stage p0 two iters later).
    if (doStage) {
      asm volatile("s_waitcnt vmcnt(4) lgkmcnt(0)" ::: "memory");
    } else {
      asm volatile("s_waitcnt vmcnt(0) lgkmcnt(0)" ::: "memory");
    }
    __builtin_amdgcn_sched_barrier(0);
    __builtin_amdgcn_s_barrier();
    __builtin_amdgcn_sched_barrier(0);
    char* t = p0; p0 = p1; p1 = p2; p2 = t;
  }
#undef STAGE_A
#undef STAGE_B

  // ---- epilogue: segment by output column block (block-uniform).
  const int seg = bcol >> 11;   // 0=Q, 1=K, 2=V
  const float* bias = (seg == 0) ? bq : ((seg == 1) ? bk : bv);
#pragma unroll
  for (int j = 0; j < 4; ++j) {
    const int gcol = bcol + wc * 64 + j * 16 + l15;
    const int n = gcol & 2047;
    const float bb = bias[n];
    const int h = n >> 7, d = n & 127;
#pragma unroll
    for (int i = 0; i < 8; ++i) {
#pragma unroll
      for (int r = 0; r < 4; ++r) {
        const int grow = brow + wr * 128 + i * 16 + g * 4 + r;   // m89 C/D map
        const int b_ = grow >> 11, s_ = grow & 2047;
        const float v = acc[i][j][r] + bb;
        if (seg == 0)
          Qs[(((size_t)b_ * 16 + h) * 2048 + s_) * 128 + d] = f2bf(v);
        else if (seg == 1)
          Ks[(((size_t)b_ * 16 + h) * 2048 + s_) * 128 + d] = f2bf(v);
        else
          Vts[(((size_t)b_ * 16 + h) * 128 + d) * 2048 + s_] = f2bf(v);
      }
    }
  }
}

// ---------------------------------------------------------------- out-proj GEMM (control)
// C = A @ B^T + bias, fp32 out. Unchanged m97-style 128^2 kernel.
__global__ __launch_bounds__(256) void gemm_bt_kernel(const ushort_t* __restrict__ A,
                                                      const ushort_t* __restrict__ B,
                                                      const float* __restrict__ bias,
                                                      float* __restrict__ Cout,
                                                      int M, int N, int K) {
  __shared__ __align__(16) char smem[16384];
  char* sA = smem;
  char* sB = smem + 8192;
  const int tid = threadIdx.x;
  const int wave = tid >> 6;
  const int lane = tid & 63;
  const int wr = wave >> 1, wc = wave & 1;
  const int brow = blockIdx.y * 128;
  const int bcol = blockIdx.x * 128;

  const f32x4 fzero = {0.f, 0.f, 0.f, 0.f};
  f32x4 acc[4][4];
#pragma unroll
  for (int i = 0; i < 4; ++i)
#pragma unroll
    for (int j = 0; j < 4; ++j) acc[i][j] = fzero;

  const int srow = lane >> 2;
  const int koff = (lane & 3) * 8;

  for (int kt = 0; kt < K; kt += 32) {
#pragma unroll
    for (int c = 0; c < 2; ++c) {
      const int ch = wave + c * 4;
      gload_lds16(A + (size_t)(brow + ch * 16 + srow) * K + kt + koff, sA + ch * 1024);
      gload_lds16(B + (size_t)(bcol + ch * 16 + srow) * K + kt + koff, sB + ch * 1024);
    }
    __syncthreads();
    bf16x8 af[4], bfr[4];
#pragma unroll
    for (int i = 0; i < 4; ++i)
      af[i] = *(const bf16x8*)(sA + (wr * 64 + i * 16 + (lane & 15)) * 64 + (lane >> 4) * 16);
#pragma unroll
    for (int j = 0; j < 4; ++j)
      bfr[j] = *(const bf16x8*)(sB + (wc * 64 + j * 16 + (lane & 15)) * 64 + (lane >> 4) * 16);
#pragma unroll
    for (int i = 0; i < 4; ++i)
#pragma unroll
      for (int j = 0; j < 4; ++j) acc[i][j] = MFMA_16x16x32(af[i], bfr[j], acc[i][j]);
    __syncthreads();
  }

#pragma unroll
  for (int i = 0; i < 4; ++i)
#pragma unroll
    for (int j = 0; j < 4; ++j)
#pragma unroll
      for (int r = 0; r < 4; ++r) {
        const int row = brow + wr * 64 + i * 16 + (lane >> 4) * 4 + r;
        const int col = bcol + wc * 64 + j * 16 + (lane & 15);
        Cout[(size_t)row * N + col] = acc[i][j][r] + bias[col];
      }
}

// ---------------------------------------------------------------- flash attention (unchanged)
__global__ __launch_bounds__(256) void attn_kernel(const ushort_t* __restrict__ Q,
                                                   const ushort_t* __restrict__ K,
                                                   const ushort_t* __restrict__ Vt,
                                                   ushort_t* __restrict__ O) {
  constexpr int S = 2048, D = 128, H = 16;
  __shared__ __align__(16) char smem[16384 + 16384 + 9216];
  char* sK = smem;
  char* sVt = smem + 16384;
  char* sP = smem + 32768;

  const int tid = threadIdx.x;
  const int wave = tid >> 6;
  const int lane = tid & 63;
  const int g = lane >> 4;
  const int l15 = lane & 15;
  const int qt = blockIdx.x & 31;
  const int bh = blockIdx.x >> 5;
  const int b = bh >> 4, h = bh & 15;

  const ushort_t* Qb = Q + (size_t)bh * S * D;
  const char* Kb = (const char*)(K + (size_t)bh * S * D);
  const char* Vtb = (const char*)(Vt + (size_t)bh * D * S);
  const int q0 = qt * 64 + wave * 16;

  bf16x8 aq[4];
  {
    const ushort_t* qrow = Qb + (size_t)(q0 + l15) * D + g * 8;
#pragma unroll
    for (int kk = 0; kk < 4; ++kk) aq[kk] = *(const bf16x8*)(qrow + kk * 32);
  }

  const char* kg[4];
  const char* vg[4];
#pragma unroll
  for (int i = 0; i < 4; ++i) {
    const int po = (wave * 4 + i) * 1024 + lane * 16;
    const int lk = po ^ (((po >> 8) & 7) << 4);
    kg[i] = Kb + (size_t)(lk >> 8) * 256 + (lk & 255);
    const int lv = po ^ (((po >> 7) & 7) << 4);
    vg[i] = Vtb + (size_t)(lv >> 7) * 4096 + (lv & 127);
  }

  const f32x4 fzero = {0.f, 0.f, 0.f, 0.f};
  f32x4 o[8];
#pragma unroll
  for (int nt = 0; nt < 8; ++nt) o[nt] = fzero;
  float row_m[4] = {-1e30f, -1e30f, -1e30f, -1e30f};
  float row_l[4] = {0.f, 0.f, 0.f, 0.f};

  char* sPw = sP + wave * 2304;
  const float scale = 0.08838834764831845f;
  const float LOG2E = 1.4426950408889634f;

  for (int kv0 = 0; kv0 < S; kv0 += 64) {
    __syncthreads();
#pragma unroll
    for (int i = 0; i < 4; ++i)
      gload_lds16(kg[i] + (size_t)kv0 * 256, sK + (wave * 4 + i) * 1024);
#pragma unroll
    for (int i = 0; i < 4; ++i)
      gload_lds16(vg[i] + (size_t)kv0 * 2, sVt + (wave * 4 + i) * 1024);
    __syncthreads();

    f32x4 sfrag[4];
#pragma unroll
    for (int nt = 0; nt < 4; ++nt) {
      sfrag[nt] = fzero;
#pragma unroll
      for (int kk = 0; kk < 4; ++kk) {
        const int row = nt * 16 + l15;
        const int la = row * 256 + kk * 64 + g * 16;
        const bf16x8 bk = *(const bf16x8*)(sK + (la ^ ((row & 7) << 4)));
        sfrag[nt] = MFMA_16x16x32(aq[kk], bk, sfrag[nt]);
      }
    }

#pragma unroll
    for (int r = 0; r < 4; ++r) {
      const float s0 = sfrag[0][r] * scale;
      const float s1 = sfrag[1][r] * scale;
      const float s2 = sfrag[2][r] * scale;
      const float s3 = sfrag[3][r] * scale;
      float mx = fmaxf(fmaxf(s0, s1), fmaxf(s2, s3));
      mx = fmaxf(mx, __shfl_xor(mx, 1));
      mx = fmaxf(mx, __shfl_xor(mx, 2));
      mx = fmaxf(mx, __shfl_xor(mx, 4));
      mx = fmaxf(mx, __shfl_xor(mx, 8));
      if (!__all(mx - row_m[r] <= 8.0f)) {
        const float nm = fmaxf(row_m[r], mx);
        const float corr = exp2f((row_m[r] - nm) * LOG2E);
        row_l[r] *= corr;
#pragma unroll
        for (int nt = 0; nt < 8; ++nt) o[nt][r] *= corr;
        row_m[r] = nm;
      }
      const float nm = row_m[r];
      const float p0 = exp2f((s0 - nm) * LOG2E);
      const float p1 = exp2f((s1 - nm) * LOG2E);
      const float p2 = exp2f((s2 - nm) * LOG2E);
      const float p3 = exp2f((s3 - nm) * LOG2E);
      float rs = (p0 + p1) + (p2 + p3);
      rs += __shfl_xor(rs, 1);
      rs += __shfl_xor(rs, 2);
      rs += __shfl_xor(rs, 4);
      rs += __shfl_xor(rs, 8);
      row_l[r] += rs;
      ushort_t* pr = (ushort_t*)(sPw + (g * 4 + r) * 144);
      pr[l15] = f2bf(p0);
      pr[16 + l15] = f2bf(p1);
      pr[32 + l15] = f2bf(p2);
      pr[48 + l15] = f2bf(p3);
    }

    const bf16x8 pa0 = *(const bf16x8*)(sPw + l15 * 144 + g * 16);
    const bf16x8 pa1 = *(const bf16x8*)(sPw + l15 * 144 + 64 + g * 16);
#pragma unroll
    for (int nt = 0; nt < 8; ++nt) {
      const int d = nt * 16 + l15;
      const int la0 = d * 128 + g * 16;
      const bf16x8 bv0 = *(const bf16x8*)(sVt + (la0 ^ ((d & 7) << 4)));
      o[nt] = MFMA_16x16x32(pa0, bv0, o[nt]);
      const bf16x8 bv1 = *(const bf16x8*)(sVt + ((la0 + 64) ^ ((d & 7) << 4)));
      o[nt] = MFMA_16x16x32(pa1, bv1, o[nt]);
    }
  }

#pragma unroll
  for (int r = 0; r < 4; ++r) {
    const float inv = 1.0f / row_l[r];
    const int srow = q0 + g * 4 + r;
    ushort_t* orow = O + ((size_t)b * S + srow) * (H * D) + h * D;
#pragma unroll
    for (int nt = 0; nt < 8; ++nt) orow[nt * 16 + l15] = f2bf(o[nt][r] * inv);
  }
}

// ---------------------------------------------------------------- launch
extern "C" void kernel_launch(void* const* d_in, const int* in_sizes, int n_in,
                              void* d_out, int out_size, void* d_ws, size_t ws_size,
                              hipStream_t stream) {
  const float* hidden = (const float*)d_in[0];
  const float* Wq = (const float*)d_in[1];
  const float* bq = (const float*)d_in[2];
  const float* Wk = (const float*)d_in[3];
  const float* bk = (const float*)d_in[4];
  const float* Wv = (const float*)d_in[5];
  const float* bv = (const float*)d_in[6];
  const float* Wo = (const float*)d_in[7];
  const float* bo = (const float*)d_in[8];

  constexpr int M = 4096, N = 2048, Kd = 2048;  // M = B*S
  char* ws = (char*)d_ws;
  // ws: hb 16M | wqkv 24M (wq|wk|wv) | wo 8M | Q 16M | K 16M | Vt 16M | AO 16M = 112M
  ushort_t* hb   = (ushort_t*)(ws);
  ushort_t* wqkv = (ushort_t*)(ws + (16u << 20));
  ushort_t* wob  = (ushort_t*)(ws + (40u << 20));
  ushort_t* Qs   = (ushort_t*)(ws + (48u << 20));
  ushort_t* Ks   = Qs + (size_t)M * N;
  ushort_t* Vts  = Ks + (size_t)M * N;
  ushort_t* AO   = Vts + (size_t)M * N;

  f2bf_kernel<<<2048, 256, 0, stream>>>(hidden, hb, M * Kd / 4);
  f2bf_kernel<<<1024, 256, 0, stream>>>(Wq, wqkv, N * Kd / 4);
  f2bf_kernel<<<1024, 256, 0, stream>>>(Wk, wqkv + (size_t)N * Kd, N * Kd / 4);
  f2bf_kernel<<<1024, 256, 0, stream>>>(Wv, wqkv + 2 * (size_t)N * Kd, N * Kd / 4);
  f2bf_kernel<<<1024, 256, 0, stream>>>(Wo, wob, N * Kd / 4);

  qkv_fused_kernel<<<384, 512, 98304, stream>>>(hb, wqkv, bq, bk, bv, Qs, Ks, Vts);
  attn_kernel<<<1024, 256, 0, stream>>>(Qs, Ks, Vts, AO);
  dim3 gg(N / 128, M / 128);
  gemm_bt_kernel<<<gg, 256, 0, stream>>>(AO, wob, bo, (float*)d_out, M, N, Kd);
}

// Round 6
// 538.350 us; speedup vs baseline: 1.2123x; 1.0394x over previous
//
#include <hip/hip_runtime.h>
#include <hip/hip_bf16.h>

// MultiHeadAttention MI355X r5 (resubmit r6 — r5 bench lost to GPU broker timeout):
//   R4 post-mortem: fused QKV ~213us (vs 225 for 3 separate) — prediction miss.
//   Root causes: (a) V-segment epilogue wrote Vt with d per-lane -> 2B stores
//   at 4KB stride (~32x write amplification for 1/3 of blocks); (b) 384 blocks
//   @ 1 block/CU = 2 rounds for 1.5 rounds of work, tail dominated by slow
//   V-blocks.
//   R5 (surgical, GEMM only; attn/out-proj/converts unchanged as controls):
//   - qkv_gemm<SWAPV> template: V-blocks issue MFMA(bfr, afr) (operand swap,
//     free output transpose since both tiles are in LDS) -> Vt stores have s
//     contiguous across lanes (coalesced, same class as R3's MODE-2 GEMM).
//   - Split launches: qkv_gemm<0> 256 blocks (Q,K; exactly 1 dispatch round),
//     qkv_gemm<1> 128 blocks (V) -> separate rocprof rows for attribution.
//   - Triple-buffered counted-vmcnt pipeline (T3/T4), setprio (T5), XOR-
//     swizzled LDS via pre-swizzled global_load_lds sources, XCD swizzle (T1)
//     all unchanged from R4.
// All bf16 MFMA 16x16x32, fp32 accum. B=2,S=2048,HID=2048,H=16,D=128.

typedef __attribute__((ext_vector_type(8))) short bf16x8;
typedef __attribute__((ext_vector_type(4))) float f32x4;
typedef unsigned short ushort_t;

#define MFMA_16x16x32(a, b, c) __builtin_amdgcn_mfma_f32_16x16x32_bf16((a), (b), (c), 0, 0, 0)

__device__ __forceinline__ ushort_t f2bf(float f) {
  unsigned int u = __builtin_bit_cast(unsigned int, f);
  u += 0x7fffu + ((u >> 16) & 1u);   // round-to-nearest-even
  return (ushort_t)(u >> 16);
}

// global -> LDS direct DMA, 16B/lane. LDS dest = wave-uniform base + lane*16;
// global src is per-lane (pre-swizzle it to realize swizzled LDS layouts).
__device__ __forceinline__ void gload_lds16(const void* g, void* lds) {
  __builtin_amdgcn_global_load_lds(
      (const __attribute__((address_space(1))) unsigned int*)g,
      (__attribute__((address_space(3))) unsigned int*)(unsigned int)(unsigned long long)lds,
      16, 0, 0);
}

// ---------------------------------------------------------------- converts
__global__ __launch_bounds__(256) void f2bf_kernel(const float* __restrict__ in,
                                                   ushort_t* __restrict__ out, int n4) {
  int i = blockIdx.x * blockDim.x + threadIdx.x;
  const int stride = gridDim.x * blockDim.x;
  for (; i < n4; i += stride) {
    const float4 v = ((const float4*)in)[i];
    ushort4 o;
    o.x = f2bf(v.x); o.y = f2bf(v.y); o.z = f2bf(v.z); o.w = f2bf(v.w);
    ((ushort4*)out)[i] = o;
  }
}

// ---------------------------------------------------------------- fused QKV GEMM
// C = A @ W^T + bias over W=[Wq;Wk;Wv]. BM=BN=256, BK=32. 512 thr / 8 waves
// (2M x 4N); per-wave 128x64; acc[8][4]. LDS 3 x 32KB buffers (96KB dynamic).
// SWAPV=0: N in [0,4096) -> Q/K split-head writes. 16 N-blocks x 16 M-blocks.
// SWAPV=1: N in [4096,6144) -> MFMA operand-swapped, coalesced Vt writes.
template <int SWAPV>
__global__ __launch_bounds__(512) void qkv_gemm(
    const ushort_t* __restrict__ A,    // hidden bf16 [4096][2048]
    const ushort_t* __restrict__ W,    // [6144][2048]
    const float* __restrict__ bq, const float* __restrict__ bk,
    const float* __restrict__ bv,
    ushort_t* __restrict__ Qs, ushort_t* __restrict__ Ks,
    ushort_t* __restrict__ Vts, int nbx, int bcol0) {
  constexpr int K = 2048, NT = K / 32;   // 64 K-tiles
  extern __shared__ char sm[];
  const int tid = threadIdx.x;
  const int wave = tid >> 6, lane = tid & 63;
  const int g = lane >> 4, l15 = lane & 15;
  const int wr = wave >> 2, wc = wave & 3;

  // T1: bijective XCD swizzle (grid % 8 == 0). Consecutive sw share 'by'
  // within a chunk -> A-panel reuse in that XCD's L2.
  const int bid = blockIdx.x;
  const int chunk = (nbx * 16) >> 3;
  const int sw = (bid & 7) * chunk + (bid >> 3);
  const int bx = sw % nbx, by = sw / nbx;
  const int brow = by * 256, bcol = bcol0 + bx * 256;

  // Per-lane pre-swizzled staging sources. Linear dest slot
  // p=(wave*2+j)*64+lane holds logical slot p^((row>>1)&3).
  const ushort_t* srcA[2];
  const ushort_t* srcB[2];
#pragma unroll
  for (int j = 0; j < 2; ++j) {
    const int p = (wave * 2 + j) * 64 + lane;
    const int row = p >> 2;
    const int col = (p & 3) ^ ((row >> 1) & 3);
    srcA[j] = A + (size_t)(brow + row) * K + col * 8;
    srcB[j] = W + (size_t)(bcol + row) * K + col * 8;
  }

  // Per-lane ds_read byte offsets (within a buffer).
  const int fph = (l15 >> 1) & 3;
  const int aOff = (wr * 128 + l15) * 64 + ((g ^ fph) << 4);
  const int bOff = (wc * 64 + l15) * 64 + ((g ^ fph) << 4) + 16384;

  char* p0 = sm;
  char* p1 = sm + 32768;
  char* p2 = sm + 65536;

#define STAGE_A(P, t)                                                        \
  {                                                                          \
    gload_lds16(srcA[0] + (t) * 32, (P) + (wave * 2 + 0) * 1024);            \
    gload_lds16(srcA[1] + (t) * 32, (P) + (wave * 2 + 1) * 1024);            \
  }
#define STAGE_B(P, t)                                                        \
  {                                                                          \
    gload_lds16(srcB[0] + (t) * 32, (P) + 16384 + (wave * 2 + 0) * 1024);    \
    gload_lds16(srcB[1] + (t) * 32, (P) + 16384 + (wave * 2 + 1) * 1024);    \
  }

  const f32x4 fzero = {0.f, 0.f, 0.f, 0.f};
  f32x4 acc[8][4];
#pragma unroll
  for (int i = 0; i < 8; ++i)
#pragma unroll
    for (int j = 0; j < 4; ++j) acc[i][j] = fzero;

  // Prologue: stage kt0 -> p0, kt1 -> p1; retire kt0's 4 loads.
  STAGE_A(p0, 0); STAGE_B(p0, 0);
  STAGE_A(p1, 1); STAGE_B(p1, 1);
  asm volatile("s_waitcnt vmcnt(4)" ::: "memory");
  __builtin_amdgcn_sched_barrier(0);
  __builtin_amdgcn_s_barrier();
  __builtin_amdgcn_sched_barrier(0);

  // Ledger (per wave): entering iter kt, outstanding = kt+1's 4 loads.
  // Iter kt stages kt+2 (+4); gate vmcnt(4) retires exactly kt+1's loads.
  for (int kt = 0; kt < NT; ++kt) {
    const bool doStage = (kt < NT - 2);
    // ---- phase 1: stage A of kt+2; compute M-quarters 0..3
    if (doStage) STAGE_A(p2, kt + 2);
    bf16x8 bfr[4], afr[4];
#pragma unroll
    for (int j = 0; j < 4; ++j) bfr[j] = *(const bf16x8*)(p0 + bOff + j * 1024);
#pragma unroll
    for (int i = 0; i < 4; ++i) afr[i] = *(const bf16x8*)(p0 + aOff + i * 1024);
    __builtin_amdgcn_s_setprio(1);
#pragma unroll
    for (int i = 0; i < 4; ++i)
#pragma unroll
      for (int j = 0; j < 4; ++j)
        acc[i][j] = SWAPV ? MFMA_16x16x32(bfr[j], afr[i], acc[i][j])
                          : MFMA_16x16x32(afr[i], bfr[j], acc[i][j]);
    __builtin_amdgcn_s_setprio(0);
    // ---- phase 2: stage B of kt+2; compute M-quarters 4..7
    if (doStage) STAGE_B(p2, kt + 2);
#pragma unroll
    for (int i = 0; i < 4; ++i) afr[i] = *(const bf16x8*)(p0 + aOff + (4 + i) * 1024);
    __builtin_amdgcn_s_setprio(1);
#pragma unroll
    for (int i = 0; i < 4; ++i)
#pragma unroll
      for (int j = 0; j < 4; ++j)
        acc[4 + i][j] = SWAPV ? MFMA_16x16x32(bfr[j], afr[i], acc[4 + i][j])
                              : MFMA_16x16x32(afr[i], bfr[j], acc[4 + i][j]);
    __builtin_amdgcn_s_setprio(0);
    // ---- gate: kt+1 ready for all waves.
    if (doStage) {
      asm volatile("s_waitcnt vmcnt(4) lgkmcnt(0)" ::: "memory");
    } else {
      asm volatile("s_waitcnt vmcnt(0) lgkmcnt(0)" ::: "memory");
    }
    __builtin_amdgcn_sched_barrier(0);
    __builtin_amdgcn_s_barrier();
    __builtin_amdgcn_sched_barrier(0);
    char* t = p0; p0 = p1; p1 = p2; p2 = t;
  }
#undef STAGE_A
#undef STAGE_B

  if (!SWAPV) {
    // ---- epilogue Q/K: rows=(b,s) from M, cols=(h,d) from N; m89 C/D map.
    const int seg = bcol >> 11;   // 0=Q, 1=K (block-uniform)
    const float* bias = (seg == 0) ? bq : bk;
    ushort_t* out = (seg == 0) ? Qs : Ks;
#pragma unroll
    for (int j = 0; j < 4; ++j) {
      const int n = (bcol + wc * 64 + j * 16 + l15) & 2047;
      const float bb = bias[n];
      const int h = n >> 7, d = n & 127;
#pragma unroll
      for (int i = 0; i < 8; ++i) {
#pragma unroll
        for (int r = 0; r < 4; ++r) {
          const int grow = brow + wr * 128 + i * 16 + g * 4 + r;
          const int b_ = grow >> 11, s_ = grow & 2047;
          out[(((size_t)b_ * 16 + h) * 2048 + s_) * 128 + d] =
              f2bf(acc[i][j][r] + bb);
        }
      }
    }
  } else {
    // ---- epilogue V (swapped): fragment rows = W-rows n, cols = H-rows m.
    // s_ = m is contiguous across l15 -> coalesced 32B stores per group.
#pragma unroll
    for (int j = 0; j < 4; ++j) {
#pragma unroll
      for (int r = 0; r < 4; ++r) {
        const int n = (bcol + wc * 64 + j * 16 + g * 4 + r) & 2047;
        const float bb = bv[n];
        const int h = n >> 7, d = n & 127;
#pragma unroll
        for (int i = 0; i < 8; ++i) {
          const int m = brow + wr * 128 + i * 16 + l15;
          const int b_ = m >> 11, s_ = m & 2047;
          Vts[(((size_t)b_ * 16 + h) * 128 + d) * 2048 + s_] =
              f2bf(acc[i][j][r] + bb);
        }
      }
    }
  }
}

// ---------------------------------------------------------------- out-proj GEMM (control)
__global__ __launch_bounds__(256) void gemm_bt_kernel(const ushort_t* __restrict__ A,
                                                      const ushort_t* __restrict__ B,
                                                      const float* __restrict__ bias,
                                                      float* __restrict__ Cout,
                                                      int M, int N, int K) {
  __shared__ __align__(16) char smem[16384];
  char* sA = smem;
  char* sB = smem + 8192;
  const int tid = threadIdx.x;
  const int wave = tid >> 6;
  const int lane = tid & 63;
  const int wr = wave >> 1, wc = wave & 1;
  const int brow = blockIdx.y * 128;
  const int bcol = blockIdx.x * 128;

  const f32x4 fzero = {0.f, 0.f, 0.f, 0.f};
  f32x4 acc[4][4];
#pragma unroll
  for (int i = 0; i < 4; ++i)
#pragma unroll
    for (int j = 0; j < 4; ++j) acc[i][j] = fzero;

  const int srow = lane >> 2;
  const int koff = (lane & 3) * 8;

  for (int kt = 0; kt < K; kt += 32) {
#pragma unroll
    for (int c = 0; c < 2; ++c) {
      const int ch = wave + c * 4;
      gload_lds16(A + (size_t)(brow + ch * 16 + srow) * K + kt + koff, sA + ch * 1024);
      gload_lds16(B + (size_t)(bcol + ch * 16 + srow) * K + kt + koff, sB + ch * 1024);
    }
    __syncthreads();
    bf16x8 af[4], bfr[4];
#pragma unroll
    for (int i = 0; i < 4; ++i)
      af[i] = *(const bf16x8*)(sA + (wr * 64 + i * 16 + (lane & 15)) * 64 + (lane >> 4) * 16);
#pragma unroll
    for (int j = 0; j < 4; ++j)
      bfr[j] = *(const bf16x8*)(sB + (wc * 64 + j * 16 + (lane & 15)) * 64 + (lane >> 4) * 16);
#pragma unroll
    for (int i = 0; i < 4; ++i)
#pragma unroll
      for (int j = 0; j < 4; ++j) acc[i][j] = MFMA_16x16x32(af[i], bfr[j], acc[i][j]);
    __syncthreads();
  }

#pragma unroll
  for (int i = 0; i < 4; ++i)
#pragma unroll
    for (int j = 0; j < 4; ++j)
#pragma unroll
      for (int r = 0; r < 4; ++r) {
        const int row = brow + wr * 64 + i * 16 + (lane >> 4) * 4 + r;
        const int col = bcol + wc * 64 + j * 16 + (lane & 15);
        Cout[(size_t)row * N + col] = acc[i][j][r] + bias[col];
      }
}

// ---------------------------------------------------------------- flash attention (unchanged)
__global__ __launch_bounds__(256) void attn_kernel(const ushort_t* __restrict__ Q,
                                                   const ushort_t* __restrict__ K,
                                                   const ushort_t* __restrict__ Vt,
                                                   ushort_t* __restrict__ O) {
  constexpr int S = 2048, D = 128, H = 16;
  __shared__ __align__(16) char smem[16384 + 16384 + 9216];
  char* sK = smem;
  char* sVt = smem + 16384;
  char* sP = smem + 32768;

  const int tid = threadIdx.x;
  const int wave = tid >> 6;
  const int lane = tid & 63;
  const int g = lane >> 4;
  const int l15 = lane & 15;
  const int qt = blockIdx.x & 31;
  const int bh = blockIdx.x >> 5;
  const int b = bh >> 4, h = bh & 15;

  const ushort_t* Qb = Q + (size_t)bh * S * D;
  const char* Kb = (const char*)(K + (size_t)bh * S * D);
  const char* Vtb = (const char*)(Vt + (size_t)bh * D * S);
  const int q0 = qt * 64 + wave * 16;

  bf16x8 aq[4];
  {
    const ushort_t* qrow = Qb + (size_t)(q0 + l15) * D + g * 8;
#pragma unroll
    for (int kk = 0; kk < 4; ++kk) aq[kk] = *(const bf16x8*)(qrow + kk * 32);
  }

  const char* kg[4];
  const char* vg[4];
#pragma unroll
  for (int i = 0; i < 4; ++i) {
    const int po = (wave * 4 + i) * 1024 + lane * 16;
    const int lk = po ^ (((po >> 8) & 7) << 4);
    kg[i] = Kb + (size_t)(lk >> 8) * 256 + (lk & 255);
    const int lv = po ^ (((po >> 7) & 7) << 4);
    vg[i] = Vtb + (size_t)(lv >> 7) * 4096 + (lv & 127);
  }

  const f32x4 fzero = {0.f, 0.f, 0.f, 0.f};
  f32x4 o[8];
#pragma unroll
  for (int nt = 0; nt < 8; ++nt) o[nt] = fzero;
  float row_m[4] = {-1e30f, -1e30f, -1e30f, -1e30f};
  float row_l[4] = {0.f, 0.f, 0.f, 0.f};

  char* sPw = sP + wave * 2304;
  const float scale = 0.08838834764831845f;
  const float LOG2E = 1.4426950408889634f;

  for (int kv0 = 0; kv0 < S; kv0 += 64) {
    __syncthreads();
#pragma unroll
    for (int i = 0; i < 4; ++i)
      gload_lds16(kg[i] + (size_t)kv0 * 256, sK + (wave * 4 + i) * 1024);
#pragma unroll
    for (int i = 0; i < 4; ++i)
      gload_lds16(vg[i] + (size_t)kv0 * 2, sVt + (wave * 4 + i) * 1024);
    __syncthreads();

    f32x4 sfrag[4];
#pragma unroll
    for (int nt = 0; nt < 4; ++nt) {
      sfrag[nt] = fzero;
#pragma unroll
      for (int kk = 0; kk < 4; ++kk) {
        const int row = nt * 16 + l15;
        const int la = row * 256 + kk * 64 + g * 16;
        const bf16x8 bk = *(const bf16x8*)(sK + (la ^ ((row & 7) << 4)));
        sfrag[nt] = MFMA_16x16x32(aq[kk], bk, sfrag[nt]);
      }
    }

#pragma unroll
    for (int r = 0; r < 4; ++r) {
      const float s0 = sfrag[0][r] * scale;
      const float s1 = sfrag[1][r] * scale;
      const float s2 = sfrag[2][r] * scale;
      const float s3 = sfrag[3][r] * scale;
      float mx = fmaxf(fmaxf(s0, s1), fmaxf(s2, s3));
      mx = fmaxf(mx, __shfl_xor(mx, 1));
      mx = fmaxf(mx, __shfl_xor(mx, 2));
      mx = fmaxf(mx, __shfl_xor(mx, 4));
      mx = fmaxf(mx, __shfl_xor(mx, 8));
      if (!__all(mx - row_m[r] <= 8.0f)) {
        const float nm = fmaxf(row_m[r], mx);
        const float corr = exp2f((row_m[r] - nm) * LOG2E);
        row_l[r] *= corr;
#pragma unroll
        for (int nt = 0; nt < 8; ++nt) o[nt][r] *= corr;
        row_m[r] = nm;
      }
      const float nm = row_m[r];
      const float p0 = exp2f((s0 - nm) * LOG2E);
      const float p1 = exp2f((s1 - nm) * LOG2E);
      const float p2 = exp2f((s2 - nm) * LOG2E);
      const float p3 = exp2f((s3 - nm) * LOG2E);
      float rs = (p0 + p1) + (p2 + p3);
      rs += __shfl_xor(rs, 1);
      rs += __shfl_xor(rs, 2);
      rs += __shfl_xor(rs, 4);
      rs += __shfl_xor(rs, 8);
      row_l[r] += rs;
      ushort_t* pr = (ushort_t*)(sPw + (g * 4 + r) * 144);
      pr[l15] = f2bf(p0);
      pr[16 + l15] = f2bf(p1);
      pr[32 + l15] = f2bf(p2);
      pr[48 + l15] = f2bf(p3);
    }

    const bf16x8 pa0 = *(const bf16x8*)(sPw + l15 * 144 + g * 16);
    const bf16x8 pa1 = *(const bf16x8*)(sPw + l15 * 144 + 64 + g * 16);
#pragma unroll
    for (int nt = 0; nt < 8; ++nt) {
      const int d = nt * 16 + l15;
      const int la0 = d * 128 + g * 16;
      const bf16x8 bv0 = *(const bf16x8*)(sVt + (la0 ^ ((d & 7) << 4)));
      o[nt] = MFMA_16x16x32(pa0, bv0, o[nt]);
      const bf16x8 bv1 = *(const bf16x8*)(sVt + ((la0 + 64) ^ ((d & 7) << 4)));
      o[nt] = MFMA_16x16x32(pa1, bv1, o[nt]);
    }
  }

#pragma unroll
  for (int r = 0; r < 4; ++r) {
    const float inv = 1.0f / row_l[r];
    const int srow = q0 + g * 4 + r;
    ushort_t* orow = O + ((size_t)b * S + srow) * (H * D) + h * D;
#pragma unroll
    for (int nt = 0; nt < 8; ++nt) orow[nt * 16 + l15] = f2bf(o[nt][r] * inv);
  }
}

// ---------------------------------------------------------------- launch
extern "C" void kernel_launch(void* const* d_in, const int* in_sizes, int n_in,
                              void* d_out, int out_size, void* d_ws, size_t ws_size,
                              hipStream_t stream) {
  const float* hidden = (const float*)d_in[0];
  const float* Wq = (const float*)d_in[1];
  const float* bq = (const float*)d_in[2];
  const float* Wk = (const float*)d_in[3];
  const float* bk = (const float*)d_in[4];
  const float* Wv = (const float*)d_in[5];
  const float* bv = (const float*)d_in[6];
  const float* Wo = (const float*)d_in[7];
  const float* bo = (const float*)d_in[8];

  constexpr int M = 4096, N = 2048, Kd = 2048;  // M = B*S
  char* ws = (char*)d_ws;
  // ws: hb 16M | wqkv 24M (wq|wk|wv) | wo 8M | Q 16M | K 16M | Vt 16M | AO 16M = 112M
  ushort_t* hb   = (ushort_t*)(ws);
  ushort_t* wqkv = (ushort_t*)(ws + (16u << 20));
  ushort_t* wob  = (ushort_t*)(ws + (40u << 20));
  ushort_t* Qs   = (ushort_t*)(ws + (48u << 20));
  ushort_t* Ks   = Qs + (size_t)M * N;
  ushort_t* Vts  = Ks + (size_t)M * N;
  ushort_t* AO   = Vts + (size_t)M * N;

  f2bf_kernel<<<2048, 256, 0, stream>>>(hidden, hb, M * Kd / 4);
  f2bf_kernel<<<1024, 256, 0, stream>>>(Wq, wqkv, N * Kd / 4);
  f2bf_kernel<<<1024, 256, 0, stream>>>(Wk, wqkv + (size_t)N * Kd, N * Kd / 4);
  f2bf_kernel<<<1024, 256, 0, stream>>>(Wv, wqkv + 2 * (size_t)N * Kd, N * Kd / 4);
  f2bf_kernel<<<1024, 256, 0, stream>>>(Wo, wob, N * Kd / 4);

  // Q/K: 16 N-blocks x 16 M-blocks = 256 blocks (exactly 1 round @ 1 blk/CU).
  qkv_gemm<0><<<256, 512, 98304, stream>>>(hb, wqkv, bq, bk, bv, Qs, Ks, Vts, 16, 0);
  // V (operand-swapped, coalesced Vt): 8 x 16 = 128 blocks.
  qkv_gemm<1><<<128, 512, 98304, stream>>>(hb, wqkv, bq, bk, bv, Qs, Ks, Vts, 8, 4096);
  attn_kernel<<<1024, 256, 0, stream>>>(Qs, Ks, Vts, AO);
  dim3 gg(N / 128, M / 128);
  gemm_bt_kernel<<<gg, 256, 0, stream>>>(AO, wob, bo, (float*)d_out, M, N, Kd);
}

// Round 7
// 489.511 us; speedup vs baseline: 1.3332x; 1.0998x over previous
//
#include <hip/hip_runtime.h>
#include <hip/hip_bf16.h>

// MultiHeadAttention MI355X r7:
//   R6 post-mortem: total 538us. attn now the largest kernel (237us, 44%),
//   MfmaUtil 12 / VALUBusy 46 — softmax VALU (~550cy/iter) vs MFMA (~160cy)
//   is the critical path. QKV split = ~179us (operand-swap fix confirmed).
//   R7 (attn softmax only; QKV/out-proj/converts untouched as controls):
//   - scale folded out of hot path: unscaled max, exp2((s-nm)*SC),
//     defer threshold 90 unscaled (== HK THR=8 scaled; identical math).
//   - fast path skips the 4-shfl max reduce: __all(local_max-row_m<=90)
//     covers all 64 lanes; reduce moved inside the rare rescale branch.
//   - row_l sum via MFMA(pa, ones): C/D map drops C[g*4+r][.] into reg r
//     of lane (g,l15) == row_l[r]'s exact layout; 2 MFMA/iter replace all
//     sum shuffles/adds.
//   - P f32->bf16 via v_cvt_pk_bf16_f32 pairs (lo/hi u16 stores).
// All bf16 MFMA 16x16x32, fp32 accum. B=2,S=2048,HID=2048,H=16,D=128.

typedef __attribute__((ext_vector_type(8))) short bf16x8;
typedef __attribute__((ext_vector_type(4))) float f32x4;
typedef unsigned short ushort_t;

#define MFMA_16x16x32(a, b, c) __builtin_amdgcn_mfma_f32_16x16x32_bf16((a), (b), (c), 0, 0, 0)

__device__ __forceinline__ ushort_t f2bf(float f) {
  unsigned int u = __builtin_bit_cast(unsigned int, f);
  u += 0x7fffu + ((u >> 16) & 1u);   // round-to-nearest-even
  return (ushort_t)(u >> 16);
}

// global -> LDS direct DMA, 16B/lane. LDS dest = wave-uniform base + lane*16;
// global src is per-lane (pre-swizzle it to realize swizzled LDS layouts).
__device__ __forceinline__ void gload_lds16(const void* g, void* lds) {
  __builtin_amdgcn_global_load_lds(
      (const __attribute__((address_space(1))) unsigned int*)g,
      (__attribute__((address_space(3))) unsigned int*)(unsigned int)(unsigned long long)lds,
      16, 0, 0);
}

// ---------------------------------------------------------------- converts
__global__ __launch_bounds__(256) void f2bf_kernel(const float* __restrict__ in,
                                                   ushort_t* __restrict__ out, int n4) {
  int i = blockIdx.x * blockDim.x + threadIdx.x;
  const int stride = gridDim.x * blockDim.x;
  for (; i < n4; i += stride) {
    const float4 v = ((const float4*)in)[i];
    ushort4 o;
    o.x = f2bf(v.x); o.y = f2bf(v.y); o.z = f2bf(v.z); o.w = f2bf(v.w);
    ((ushort4*)out)[i] = o;
  }
}

// ---------------------------------------------------------------- fused QKV GEMM
// C = A @ W^T + bias over W=[Wq;Wk;Wv]. BM=BN=256, BK=32. 512 thr / 8 waves
// (2M x 4N); per-wave 128x64; acc[8][4]. LDS 3 x 32KB buffers (96KB dynamic).
// SWAPV=0: N in [0,4096) -> Q/K split-head writes. SWAPV=1: operand-swapped
// MFMA -> transposed tile -> coalesced Vt writes.
template <int SWAPV>
__global__ __launch_bounds__(512) void qkv_gemm(
    const ushort_t* __restrict__ A,    // hidden bf16 [4096][2048]
    const ushort_t* __restrict__ W,    // [6144][2048]
    const float* __restrict__ bq, const float* __restrict__ bk,
    const float* __restrict__ bv,
    ushort_t* __restrict__ Qs, ushort_t* __restrict__ Ks,
    ushort_t* __restrict__ Vts, int nbx, int bcol0) {
  constexpr int K = 2048, NT = K / 32;   // 64 K-tiles
  extern __shared__ char sm[];
  const int tid = threadIdx.x;
  const int wave = tid >> 6, lane = tid & 63;
  const int g = lane >> 4, l15 = lane & 15;
  const int wr = wave >> 2, wc = wave & 3;

  // T1: bijective XCD swizzle (grid % 8 == 0).
  const int bid = blockIdx.x;
  const int chunk = (nbx * 16) >> 3;
  const int sw = (bid & 7) * chunk + (bid >> 3);
  const int bx = sw % nbx, by = sw / nbx;
  const int brow = by * 256, bcol = bcol0 + bx * 256;

  // Per-lane pre-swizzled staging sources. Linear dest slot
  // p=(wave*2+j)*64+lane holds logical slot p^((row>>1)&3).
  const ushort_t* srcA[2];
  const ushort_t* srcB[2];
#pragma unroll
  for (int j = 0; j < 2; ++j) {
    const int p = (wave * 2 + j) * 64 + lane;
    const int row = p >> 2;
    const int col = (p & 3) ^ ((row >> 1) & 3);
    srcA[j] = A + (size_t)(brow + row) * K + col * 8;
    srcB[j] = W + (size_t)(bcol + row) * K + col * 8;
  }

  const int fph = (l15 >> 1) & 3;
  const int aOff = (wr * 128 + l15) * 64 + ((g ^ fph) << 4);
  const int bOff = (wc * 64 + l15) * 64 + ((g ^ fph) << 4) + 16384;

  char* p0 = sm;
  char* p1 = sm + 32768;
  char* p2 = sm + 65536;

#define STAGE_A(P, t)                                                        \
  {                                                                          \
    gload_lds16(srcA[0] + (t) * 32, (P) + (wave * 2 + 0) * 1024);            \
    gload_lds16(srcA[1] + (t) * 32, (P) + (wave * 2 + 1) * 1024);            \
  }
#define STAGE_B(P, t)                                                        \
  {                                                                          \
    gload_lds16(srcB[0] + (t) * 32, (P) + 16384 + (wave * 2 + 0) * 1024);    \
    gload_lds16(srcB[1] + (t) * 32, (P) + 16384 + (wave * 2 + 1) * 1024);    \
  }

  const f32x4 fzero = {0.f, 0.f, 0.f, 0.f};
  f32x4 acc[8][4];
#pragma unroll
  for (int i = 0; i < 8; ++i)
#pragma unroll
    for (int j = 0; j < 4; ++j) acc[i][j] = fzero;

  STAGE_A(p0, 0); STAGE_B(p0, 0);
  STAGE_A(p1, 1); STAGE_B(p1, 1);
  asm volatile("s_waitcnt vmcnt(4)" ::: "memory");
  __builtin_amdgcn_sched_barrier(0);
  __builtin_amdgcn_s_barrier();
  __builtin_amdgcn_sched_barrier(0);

  // Ledger: entering iter kt, outstanding = kt+1's 4 loads; iter kt stages
  // kt+2 (+4); gate vmcnt(4) retires exactly kt+1's loads.
  for (int kt = 0; kt < NT; ++kt) {
    const bool doStage = (kt < NT - 2);
    if (doStage) STAGE_A(p2, kt + 2);
    bf16x8 bfr[4], afr[4];
#pragma unroll
    for (int j = 0; j < 4; ++j) bfr[j] = *(const bf16x8*)(p0 + bOff + j * 1024);
#pragma unroll
    for (int i = 0; i < 4; ++i) afr[i] = *(const bf16x8*)(p0 + aOff + i * 1024);
    __builtin_amdgcn_s_setprio(1);
#pragma unroll
    for (int i = 0; i < 4; ++i)
#pragma unroll
      for (int j = 0; j < 4; ++j)
        acc[i][j] = SWAPV ? MFMA_16x16x32(bfr[j], afr[i], acc[i][j])
                          : MFMA_16x16x32(afr[i], bfr[j], acc[i][j]);
    __builtin_amdgcn_s_setprio(0);
    if (doStage) STAGE_B(p2, kt + 2);
#pragma unroll
    for (int i = 0; i < 4; ++i) afr[i] = *(const bf16x8*)(p0 + aOff + (4 + i) * 1024);
    __builtin_amdgcn_s_setprio(1);
#pragma unroll
    for (int i = 0; i < 4; ++i)
#pragma unroll
      for (int j = 0; j < 4; ++j)
        acc[4 + i][j] = SWAPV ? MFMA_16x16x32(bfr[j], afr[i], acc[4 + i][j])
                              : MFMA_16x16x32(afr[i], bfr[j], acc[4 + i][j]);
    __builtin_amdgcn_s_setprio(0);
    if (doStage) {
      asm volatile("s_waitcnt vmcnt(4) lgkmcnt(0)" ::: "memory");
    } else {
      asm volatile("s_waitcnt vmcnt(0) lgkmcnt(0)" ::: "memory");
    }
    __builtin_amdgcn_sched_barrier(0);
    __builtin_amdgcn_s_barrier();
    __builtin_amdgcn_sched_barrier(0);
    char* t = p0; p0 = p1; p1 = p2; p2 = t;
  }
#undef STAGE_A
#undef STAGE_B

  if (!SWAPV) {
    const int seg = bcol >> 11;   // 0=Q, 1=K (block-uniform)
    const float* bias = (seg == 0) ? bq : bk;
    ushort_t* out = (seg == 0) ? Qs : Ks;
#pragma unroll
    for (int j = 0; j < 4; ++j) {
      const int n = (bcol + wc * 64 + j * 16 + l15) & 2047;
      const float bb = bias[n];
      const int h = n >> 7, d = n & 127;
#pragma unroll
      for (int i = 0; i < 8; ++i) {
#pragma unroll
        for (int r = 0; r < 4; ++r) {
          const int grow = brow + wr * 128 + i * 16 + g * 4 + r;
          const int b_ = grow >> 11, s_ = grow & 2047;
          out[(((size_t)b_ * 16 + h) * 2048 + s_) * 128 + d] =
              f2bf(acc[i][j][r] + bb);
        }
      }
    }
  } else {
#pragma unroll
    for (int j = 0; j < 4; ++j) {
#pragma unroll
      for (int r = 0; r < 4; ++r) {
        const int n = (bcol + wc * 64 + j * 16 + g * 4 + r) & 2047;
        const float bb = bv[n];
        const int h = n >> 7, d = n & 127;
#pragma unroll
        for (int i = 0; i < 8; ++i) {
          const int m = brow + wr * 128 + i * 16 + l15;
          const int b_ = m >> 11, s_ = m & 2047;
          Vts[(((size_t)b_ * 16 + h) * 128 + d) * 2048 + s_] =
              f2bf(acc[i][j][r] + bb);
        }
      }
    }
  }
}

// ---------------------------------------------------------------- out-proj GEMM (control)
__global__ __launch_bounds__(256) void gemm_bt_kernel(const ushort_t* __restrict__ A,
                                                      const ushort_t* __restrict__ B,
                                                      const float* __restrict__ bias,
                                                      float* __restrict__ Cout,
                                                      int M, int N, int K) {
  __shared__ __align__(16) char smem[16384];
  char* sA = smem;
  char* sB = smem + 8192;
  const int tid = threadIdx.x;
  const int wave = tid >> 6;
  const int lane = tid & 63;
  const int wr = wave >> 1, wc = wave & 1;
  const int brow = blockIdx.y * 128;
  const int bcol = blockIdx.x * 128;

  const f32x4 fzero = {0.f, 0.f, 0.f, 0.f};
  f32x4 acc[4][4];
#pragma unroll
  for (int i = 0; i < 4; ++i)
#pragma unroll
    for (int j = 0; j < 4; ++j) acc[i][j] = fzero;

  const int srow = lane >> 2;
  const int koff = (lane & 3) * 8;

  for (int kt = 0; kt < K; kt += 32) {
#pragma unroll
    for (int c = 0; c < 2; ++c) {
      const int ch = wave + c * 4;
      gload_lds16(A + (size_t)(brow + ch * 16 + srow) * K + kt + koff, sA + ch * 1024);
      gload_lds16(B + (size_t)(bcol + ch * 16 + srow) * K + kt + koff, sB + ch * 1024);
    }
    __syncthreads();
    bf16x8 af[4], bfr[4];
#pragma unroll
    for (int i = 0; i < 4; ++i)
      af[i] = *(const bf16x8*)(sA + (wr * 64 + i * 16 + (lane & 15)) * 64 + (lane >> 4) * 16);
#pragma unroll
    for (int j = 0; j < 4; ++j)
      bfr[j] = *(const bf16x8*)(sB + (wc * 64 + j * 16 + (lane & 15)) * 64 + (lane >> 4) * 16);
#pragma unroll
    for (int i = 0; i < 4; ++i)
#pragma unroll
      for (int j = 0; j < 4; ++j) acc[i][j] = MFMA_16x16x32(af[i], bfr[j], acc[i][j]);
    __syncthreads();
  }

#pragma unroll
  for (int i = 0; i < 4; ++i)
#pragma unroll
    for (int j = 0; j < 4; ++j)
#pragma unroll
      for (int r = 0; r < 4; ++r) {
        const int row = brow + wr * 64 + i * 16 + (lane >> 4) * 4 + r;
        const int col = bcol + wc * 64 + j * 16 + (lane & 15);
        Cout[(size_t)row * N + col] = acc[i][j][r] + bias[col];
      }
}

// ---------------------------------------------------------------- flash attention
// grid: 1024 = (B*H=32) x (S/64=32 q-tiles); 4 waves x 16 q-rows; KVBLK=64.
__global__ __launch_bounds__(256) void attn_kernel(const ushort_t* __restrict__ Q,
                                                   const ushort_t* __restrict__ K,
                                                   const ushort_t* __restrict__ Vt,
                                                   ushort_t* __restrict__ O) {
  constexpr int S = 2048, D = 128, H = 16;
  __shared__ __align__(16) char smem[16384 + 16384 + 9216];
  char* sK = smem;
  char* sVt = smem + 16384;
  char* sP = smem + 32768;

  const int tid = threadIdx.x;
  const int wave = tid >> 6;
  const int lane = tid & 63;
  const int g = lane >> 4;
  const int l15 = lane & 15;
  const int qt = blockIdx.x & 31;
  const int bh = blockIdx.x >> 5;
  const int b = bh >> 4, h = bh & 15;

  const ushort_t* Qb = Q + (size_t)bh * S * D;
  const char* Kb = (const char*)(K + (size_t)bh * S * D);
  const char* Vtb = (const char*)(Vt + (size_t)bh * D * S);
  const int q0 = qt * 64 + wave * 16;

  bf16x8 aq[4];
  {
    const ushort_t* qrow = Qb + (size_t)(q0 + l15) * D + g * 8;
#pragma unroll
    for (int kk = 0; kk < 4; ++kk) aq[kk] = *(const bf16x8*)(qrow + kk * 32);
  }

  const char* kg[4];
  const char* vg[4];
#pragma unroll
  for (int i = 0; i < 4; ++i) {
    const int po = (wave * 4 + i) * 1024 + lane * 16;
    const int lk = po ^ (((po >> 8) & 7) << 4);
    kg[i] = Kb + (size_t)(lk >> 8) * 256 + (lk & 255);
    const int lv = po ^ (((po >> 7) & 7) << 4);
    vg[i] = Vtb + (size_t)(lv >> 7) * 4096 + (lv & 127);
  }

  const f32x4 fzero = {0.f, 0.f, 0.f, 0.f};
  f32x4 o[8];
#pragma unroll
  for (int nt = 0; nt < 8; ++nt) o[nt] = fzero;
  float row_m[4] = {-1e30f, -1e30f, -1e30f, -1e30f};
  float row_l[4] = {0.f, 0.f, 0.f, 0.f};

  // ones B-fragment for row-sum MFMA (any layout: all elements 1.0bf16)
  bf16x8 ones;
#pragma unroll
  for (int i = 0; i < 8; ++i) ones[i] = (short)0x3F80;

  char* sPw = sP + wave * 2304;
  // scale folded: p = exp2((s_raw - m_raw)*SC), SC = (1/sqrt(128))*log2(e).
  const float SC = 0.12751746f;
  // defer-max threshold in raw units: 8 (scaled, == HK THR) / scale = 90.5.
  const float THR = 90.0f;

  for (int kv0 = 0; kv0 < S; kv0 += 64) {
    __syncthreads();
#pragma unroll
    for (int i = 0; i < 4; ++i)
      gload_lds16(kg[i] + (size_t)kv0 * 256, sK + (wave * 4 + i) * 1024);
#pragma unroll
    for (int i = 0; i < 4; ++i)
      gload_lds16(vg[i] + (size_t)kv0 * 2, sVt + (wave * 4 + i) * 1024);
    __syncthreads();

    // ---- S = Q K^T (raw, unscaled): 4 x (16 kv-cols) tiles
    f32x4 sfrag[4];
#pragma unroll
    for (int nt = 0; nt < 4; ++nt) {
      sfrag[nt] = fzero;
#pragma unroll
      for (int kk = 0; kk < 4; ++kk) {
        const int row = nt * 16 + l15;
        const int la = row * 256 + kk * 64 + g * 16;
        const bf16x8 bk = *(const bf16x8*)(sK + (la ^ ((row & 7) << 4)));
        sfrag[nt] = MFMA_16x16x32(aq[kk], bk, sfrag[nt]);
      }
    }

    // ---- online softmax; lane holds S[q=g*4+r][kv=nt*16+l15].
    // Fast path: no max reduce (the __all covers all 64 lanes); reduce+rescale
    // only inside the rare branch (effectively iter 0 for this data).
#pragma unroll
    for (int r = 0; r < 4; ++r) {
      const float s0 = sfrag[0][r];
      const float s1 = sfrag[1][r];
      const float s2 = sfrag[2][r];
      const float s3 = sfrag[3][r];
      const float lm = fmaxf(fmaxf(s0, s1), fmaxf(s2, s3));
      if (!__all(lm - row_m[r] <= THR)) {   // wave-uniform branch
        float mx = lm;
        mx = fmaxf(mx, __shfl_xor(mx, 1));
        mx = fmaxf(mx, __shfl_xor(mx, 2));
        mx = fmaxf(mx, __shfl_xor(mx, 4));
        mx = fmaxf(mx, __shfl_xor(mx, 8));
        const float nm = fmaxf(row_m[r], mx);
        const float corr = exp2f((row_m[r] - nm) * SC);
        row_l[r] *= corr;
#pragma unroll
        for (int nt = 0; nt < 8; ++nt) o[nt][r] *= corr;
        row_m[r] = nm;
      }
      const float nm = row_m[r];
      const float p0 = exp2f((s0 - nm) * SC);
      const float p1 = exp2f((s1 - nm) * SC);
      const float p2 = exp2f((s2 - nm) * SC);
      const float p3 = exp2f((s3 - nm) * SC);
      unsigned int pk01, pk23;
      asm("v_cvt_pk_bf16_f32 %0, %1, %2" : "=v"(pk01) : "v"(p0), "v"(p1));
      asm("v_cvt_pk_bf16_f32 %0, %1, %2" : "=v"(pk23) : "v"(p2), "v"(p3));
      ushort_t* pr = (ushort_t*)(sPw + (g * 4 + r) * 144);
      pr[l15] = (ushort_t)(pk01 & 0xffffu);
      pr[16 + l15] = (ushort_t)(pk01 >> 16);
      pr[32 + l15] = (ushort_t)(pk23 & 0xffffu);
      pr[48 + l15] = (ushort_t)(pk23 >> 16);
    }

    // ---- O += P V; row_l += P·1 via MFMA (C[g*4+r][.] lands in reg r of
    // lane (g,l15) == row_l[r]'s exact layout; all cols identical).
    const bf16x8 pa0 = *(const bf16x8*)(sPw + l15 * 144 + g * 16);
    const bf16x8 pa1 = *(const bf16x8*)(sPw + l15 * 144 + 64 + g * 16);
    f32x4 lfrag = fzero;
    lfrag = MFMA_16x16x32(pa0, ones, lfrag);
    lfrag = MFMA_16x16x32(pa1, ones, lfrag);
#pragma unroll
    for (int nt = 0; nt < 8; ++nt) {
      const int d = nt * 16 + l15;
      const int la0 = d * 128 + g * 16;
      const bf16x8 bv0 = *(const bf16x8*)(sVt + (la0 ^ ((d & 7) << 4)));
      o[nt] = MFMA_16x16x32(pa0, bv0, o[nt]);
      const bf16x8 bv1 = *(const bf16x8*)(sVt + ((la0 + 64) ^ ((d & 7) << 4)));
      o[nt] = MFMA_16x16x32(pa1, bv1, o[nt]);
    }
#pragma unroll
    for (int r = 0; r < 4; ++r) row_l[r] += lfrag[r];
  }

  // ---- epilogue: O/l -> bf16 [B*S][H*D] (A-input of out-proj)
#pragma unroll
  for (int r = 0; r < 4; ++r) {
    const float inv = 1.0f / row_l[r];
    const int srow = q0 + g * 4 + r;
    ushort_t* orow = O + ((size_t)b * S + srow) * (H * D) + h * D;
#pragma unroll
    for (int nt = 0; nt < 8; ++nt) orow[nt * 16 + l15] = f2bf(o[nt][r] * inv);
  }
}

// ---------------------------------------------------------------- launch
extern "C" void kernel_launch(void* const* d_in, const int* in_sizes, int n_in,
                              void* d_out, int out_size, void* d_ws, size_t ws_size,
                              hipStream_t stream) {
  const float* hidden = (const float*)d_in[0];
  const float* Wq = (const float*)d_in[1];
  const float* bq = (const float*)d_in[2];
  const float* Wk = (const float*)d_in[3];
  const float* bk = (const float*)d_in[4];
  const float* Wv = (const float*)d_in[5];
  const float* bv = (const float*)d_in[6];
  const float* Wo = (const float*)d_in[7];
  const float* bo = (const float*)d_in[8];

  constexpr int M = 4096, N = 2048, Kd = 2048;  // M = B*S
  char* ws = (char*)d_ws;
  // ws: hb 16M | wqkv 24M (wq|wk|wv) | wo 8M | Q 16M | K 16M | Vt 16M | AO 16M = 112M
  ushort_t* hb   = (ushort_t*)(ws);
  ushort_t* wqkv = (ushort_t*)(ws + (16u << 20));
  ushort_t* wob  = (ushort_t*)(ws + (40u << 20));
  ushort_t* Qs   = (ushort_t*)(ws + (48u << 20));
  ushort_t* Ks   = Qs + (size_t)M * N;
  ushort_t* Vts  = Ks + (size_t)M * N;
  ushort_t* AO   = Vts + (size_t)M * N;

  f2bf_kernel<<<2048, 256, 0, stream>>>(hidden, hb, M * Kd / 4);
  f2bf_kernel<<<1024, 256, 0, stream>>>(Wq, wqkv, N * Kd / 4);
  f2bf_kernel<<<1024, 256, 0, stream>>>(Wk, wqkv + (size_t)N * Kd, N * Kd / 4);
  f2bf_kernel<<<1024, 256, 0, stream>>>(Wv, wqkv + 2 * (size_t)N * Kd, N * Kd / 4);
  f2bf_kernel<<<1024, 256, 0, stream>>>(Wo, wob, N * Kd / 4);

  // Q/K: 16 N-blocks x 16 M-blocks = 256 blocks (exactly 1 round @ 1 blk/CU).
  qkv_gemm<0><<<256, 512, 98304, stream>>>(hb, wqkv, bq, bk, bv, Qs, Ks, Vts, 16, 0);
  // V (operand-swapped, coalesced Vt): 8 x 16 = 128 blocks.
  qkv_gemm<1><<<128, 512, 98304, stream>>>(hb, wqkv, bq, bk, bv, Qs, Ks, Vts, 8, 4096);
  attn_kernel<<<1024, 256, 0, stream>>>(Qs, Ks, Vts, AO);
  dim3 gg(N / 128, M / 128);
  gemm_bt_kernel<<<gg, 256, 0, stream>>>(AO, wob, bo, (float*)d_out, M, N, Kd);
}

// Round 8
// 485.443 us; speedup vs baseline: 1.3444x; 1.0084x over previous
//
#include <hip/hip_runtime.h>
#include <hip/hip_bf16.h>

// MultiHeadAttention MI355X r8:
//   R7 post-mortem: attn 237->168.7us (prediction matched). Remaining budget
//   is non-attn ~320us but attribution is subtraction-only (top-5 rocprof rows
//   are all attn replays) and two models for QKV disagree (40-60 vs ~180us).
//   R8 = attribution + safe wins:
//   - attn split into 2 dispatches (bh0 param, 512 blocks each, ~84us) so the
//     next-longest kernel surfaces in top-5 with real counters.
//   - out-proj ported to the proven 256^2 2-phase counted-vmcnt template
//     (oproj_gemm, fp32 coalesced epilogue, 128 blocks).
//   - 4 weight converts merged into one dispatch (f2bfw_kernel).
//   - qkv_gemm<0/1> byte-identical to R7 (control).
// All bf16 MFMA 16x16x32, fp32 accum. B=2,S=2048,HID=2048,H=16,D=128.

typedef __attribute__((ext_vector_type(8))) short bf16x8;
typedef __attribute__((ext_vector_type(4))) float f32x4;
typedef unsigned short ushort_t;

#define MFMA_16x16x32(a, b, c) __builtin_amdgcn_mfma_f32_16x16x32_bf16((a), (b), (c), 0, 0, 0)

__device__ __forceinline__ ushort_t f2bf(float f) {
  unsigned int u = __builtin_bit_cast(unsigned int, f);
  u += 0x7fffu + ((u >> 16) & 1u);   // round-to-nearest-even
  return (ushort_t)(u >> 16);
}

// global -> LDS direct DMA, 16B/lane. LDS dest = wave-uniform base + lane*16;
// global src is per-lane (pre-swizzle it to realize swizzled LDS layouts).
__device__ __forceinline__ void gload_lds16(const void* g, void* lds) {
  __builtin_amdgcn_global_load_lds(
      (const __attribute__((address_space(1))) unsigned int*)g,
      (__attribute__((address_space(3))) unsigned int*)(unsigned int)(unsigned long long)lds,
      16, 0, 0);
}

// ---------------------------------------------------------------- converts
__global__ __launch_bounds__(256) void f2bf_kernel(const float* __restrict__ in,
                                                   ushort_t* __restrict__ out, int n4) {
  int i = blockIdx.x * blockDim.x + threadIdx.x;
  const int stride = gridDim.x * blockDim.x;
  for (; i < n4; i += stride) {
    const float4 v = ((const float4*)in)[i];
    ushort4 o;
    o.x = f2bf(v.x); o.y = f2bf(v.y); o.z = f2bf(v.z); o.w = f2bf(v.w);
    ((ushort4*)out)[i] = o;
  }
}

// all 4 weight matrices in one dispatch: 4 segs x 512 blocks, grid-stride.
__global__ __launch_bounds__(256) void f2bfw_kernel(
    const float* __restrict__ w0, const float* __restrict__ w1,
    const float* __restrict__ w2, const float* __restrict__ w3,
    ushort_t* __restrict__ o0, ushort_t* __restrict__ o1,
    ushort_t* __restrict__ o2, ushort_t* __restrict__ o3) {
  const int seg = blockIdx.x >> 9;
  const int bid = blockIdx.x & 511;
  const float* in = (seg == 0) ? w0 : (seg == 1) ? w1 : (seg == 2) ? w2 : w3;
  ushort_t* out = (seg == 0) ? o0 : (seg == 1) ? o1 : (seg == 2) ? o2 : o3;
  constexpr int n4 = 2048 * 2048 / 4;
  for (int i = bid * 256 + (int)threadIdx.x; i < n4; i += 512 * 256) {
    const float4 v = ((const float4*)in)[i];
    ushort4 o;
    o.x = f2bf(v.x); o.y = f2bf(v.y); o.z = f2bf(v.z); o.w = f2bf(v.w);
    ((ushort4*)out)[i] = o;
  }
}

// ---------------------------------------------------------------- fused QKV GEMM (control, == R7)
// C = A @ W^T + bias over W=[Wq;Wk;Wv]. BM=BN=256, BK=32. 512 thr / 8 waves
// (2M x 4N); per-wave 128x64; acc[8][4]. LDS 3 x 32KB buffers (96KB dynamic).
template <int SWAPV>
__global__ __launch_bounds__(512) void qkv_gemm(
    const ushort_t* __restrict__ A,    // hidden bf16 [4096][2048]
    const ushort_t* __restrict__ W,    // [6144][2048]
    const float* __restrict__ bq, const float* __restrict__ bk,
    const float* __restrict__ bv,
    ushort_t* __restrict__ Qs, ushort_t* __restrict__ Ks,
    ushort_t* __restrict__ Vts, int nbx, int bcol0) {
  constexpr int K = 2048, NT = K / 32;   // 64 K-tiles
  extern __shared__ char sm[];
  const int tid = threadIdx.x;
  const int wave = tid >> 6, lane = tid & 63;
  const int g = lane >> 4, l15 = lane & 15;
  const int wr = wave >> 2, wc = wave & 3;

  const int bid = blockIdx.x;
  const int chunk = (nbx * 16) >> 3;
  const int sw = (bid & 7) * chunk + (bid >> 3);
  const int bx = sw % nbx, by = sw / nbx;
  const int brow = by * 256, bcol = bcol0 + bx * 256;

  const ushort_t* srcA[2];
  const ushort_t* srcB[2];
#pragma unroll
  for (int j = 0; j < 2; ++j) {
    const int p = (wave * 2 + j) * 64 + lane;
    const int row = p >> 2;
    const int col = (p & 3) ^ ((row >> 1) & 3);
    srcA[j] = A + (size_t)(brow + row) * K + col * 8;
    srcB[j] = W + (size_t)(bcol + row) * K + col * 8;
  }

  const int fph = (l15 >> 1) & 3;
  const int aOff = (wr * 128 + l15) * 64 + ((g ^ fph) << 4);
  const int bOff = (wc * 64 + l15) * 64 + ((g ^ fph) << 4) + 16384;

  char* p0 = sm;
  char* p1 = sm + 32768;
  char* p2 = sm + 65536;

#define STAGE_A(P, t)                                                        \
  {                                                                          \
    gload_lds16(srcA[0] + (t) * 32, (P) + (wave * 2 + 0) * 1024);            \
    gload_lds16(srcA[1] + (t) * 32, (P) + (wave * 2 + 1) * 1024);            \
  }
#define STAGE_B(P, t)                                                        \
  {                                                                          \
    gload_lds16(srcB[0] + (t) * 32, (P) + 16384 + (wave * 2 + 0) * 1024);    \
    gload_lds16(srcB[1] + (t) * 32, (P) + 16384 + (wave * 2 + 1) * 1024);    \
  }

  const f32x4 fzero = {0.f, 0.f, 0.f, 0.f};
  f32x4 acc[8][4];
#pragma unroll
  for (int i = 0; i < 8; ++i)
#pragma unroll
    for (int j = 0; j < 4; ++j) acc[i][j] = fzero;

  STAGE_A(p0, 0); STAGE_B(p0, 0);
  STAGE_A(p1, 1); STAGE_B(p1, 1);
  asm volatile("s_waitcnt vmcnt(4)" ::: "memory");
  __builtin_amdgcn_sched_barrier(0);
  __builtin_amdgcn_s_barrier();
  __builtin_amdgcn_sched_barrier(0);

  for (int kt = 0; kt < NT; ++kt) {
    const bool doStage = (kt < NT - 2);
    if (doStage) STAGE_A(p2, kt + 2);
    bf16x8 bfr[4], afr[4];
#pragma unroll
    for (int j = 0; j < 4; ++j) bfr[j] = *(const bf16x8*)(p0 + bOff + j * 1024);
#pragma unroll
    for (int i = 0; i < 4; ++i) afr[i] = *(const bf16x8*)(p0 + aOff + i * 1024);
    __builtin_amdgcn_s_setprio(1);
#pragma unroll
    for (int i = 0; i < 4; ++i)
#pragma unroll
      for (int j = 0; j < 4; ++j)
        acc[i][j] = SWAPV ? MFMA_16x16x32(bfr[j], afr[i], acc[i][j])
                          : MFMA_16x16x32(afr[i], bfr[j], acc[i][j]);
    __builtin_amdgcn_s_setprio(0);
    if (doStage) STAGE_B(p2, kt + 2);
#pragma unroll
    for (int i = 0; i < 4; ++i) afr[i] = *(const bf16x8*)(p0 + aOff + (4 + i) * 1024);
    __builtin_amdgcn_s_setprio(1);
#pragma unroll
    for (int i = 0; i < 4; ++i)
#pragma unroll
      for (int j = 0; j < 4; ++j)
        acc[4 + i][j] = SWAPV ? MFMA_16x16x32(bfr[j], afr[i], acc[4 + i][j])
                              : MFMA_16x16x32(afr[i], bfr[j], acc[4 + i][j]);
    __builtin_amdgcn_s_setprio(0);
    if (doStage) {
      asm volatile("s_waitcnt vmcnt(4) lgkmcnt(0)" ::: "memory");
    } else {
      asm volatile("s_waitcnt vmcnt(0) lgkmcnt(0)" ::: "memory");
    }
    __builtin_amdgcn_sched_barrier(0);
    __builtin_amdgcn_s_barrier();
    __builtin_amdgcn_sched_barrier(0);
    char* t = p0; p0 = p1; p1 = p2; p2 = t;
  }
#undef STAGE_A
#undef STAGE_B

  if (!SWAPV) {
    const int seg = bcol >> 11;   // 0=Q, 1=K (block-uniform)
    const float* bias = (seg == 0) ? bq : bk;
    ushort_t* out = (seg == 0) ? Qs : Ks;
#pragma unroll
    for (int j = 0; j < 4; ++j) {
      const int n = (bcol + wc * 64 + j * 16 + l15) & 2047;
      const float bb = bias[n];
      const int h = n >> 7, d = n & 127;
#pragma unroll
      for (int i = 0; i < 8; ++i) {
#pragma unroll
        for (int r = 0; r < 4; ++r) {
          const int grow = brow + wr * 128 + i * 16 + g * 4 + r;
          const int b_ = grow >> 11, s_ = grow & 2047;
          out[(((size_t)b_ * 16 + h) * 2048 + s_) * 128 + d] =
              f2bf(acc[i][j][r] + bb);
        }
      }
    }
  } else {
#pragma unroll
    for (int j = 0; j < 4; ++j) {
#pragma unroll
      for (int r = 0; r < 4; ++r) {
        const int n = (bcol + wc * 64 + j * 16 + g * 4 + r) & 2047;
        const float bb = bv[n];
        const int h = n >> 7, d = n & 127;
#pragma unroll
        for (int i = 0; i < 8; ++i) {
          const int m = brow + wr * 128 + i * 16 + l15;
          const int b_ = m >> 11, s_ = m & 2047;
          Vts[(((size_t)b_ * 16 + h) * 128 + d) * 2048 + s_] =
              f2bf(acc[i][j][r] + bb);
        }
      }
    }
  }
}

// ---------------------------------------------------------------- out-proj GEMM (256^2 pipelined)
// C = A @ W^T + bias, fp32 out [4096][2048]. Same template as qkv_gemm.
__global__ __launch_bounds__(512) void oproj_gemm(
    const ushort_t* __restrict__ A,    // AO bf16 [4096][2048]
    const ushort_t* __restrict__ W,    // wob [2048][2048]
    const float* __restrict__ bias, float* __restrict__ Cout) {
  constexpr int K = 2048, NT = K / 32, nbx = 8;
  extern __shared__ char sm[];
  const int tid = threadIdx.x;
  const int wave = tid >> 6, lane = tid & 63;
  const int g = lane >> 4, l15 = lane & 15;
  const int wr = wave >> 2, wc = wave & 3;

  const int bid = blockIdx.x;                 // 128 blocks (16 M x 8 N)
  const int chunk = (nbx * 16) >> 3;          // 16
  const int sw = (bid & 7) * chunk + (bid >> 3);
  const int bx = sw % nbx, by = sw / nbx;
  const int brow = by * 256, bcol = bx * 256;

  const ushort_t* srcA[2];
  const ushort_t* srcB[2];
#pragma unroll
  for (int j = 0; j < 2; ++j) {
    const int p = (wave * 2 + j) * 64 + lane;
    const int row = p >> 2;
    const int col = (p & 3) ^ ((row >> 1) & 3);
    srcA[j] = A + (size_t)(brow + row) * K + col * 8;
    srcB[j] = W + (size_t)(bcol + row) * K + col * 8;
  }

  const int fph = (l15 >> 1) & 3;
  const int aOff = (wr * 128 + l15) * 64 + ((g ^ fph) << 4);
  const int bOff = (wc * 64 + l15) * 64 + ((g ^ fph) << 4) + 16384;

  char* p0 = sm;
  char* p1 = sm + 32768;
  char* p2 = sm + 65536;

#define STAGE_A(P, t)                                                        \
  {                                                                          \
    gload_lds16(srcA[0] + (t) * 32, (P) + (wave * 2 + 0) * 1024);            \
    gload_lds16(srcA[1] + (t) * 32, (P) + (wave * 2 + 1) * 1024);            \
  }
#define STAGE_B(P, t)                                                        \
  {                                                                          \
    gload_lds16(srcB[0] + (t) * 32, (P) + 16384 + (wave * 2 + 0) * 1024);    \
    gload_lds16(srcB[1] + (t) * 32, (P) + 16384 + (wave * 2 + 1) * 1024);    \
  }

  const f32x4 fzero = {0.f, 0.f, 0.f, 0.f};
  f32x4 acc[8][4];
#pragma unroll
  for (int i = 0; i < 8; ++i)
#pragma unroll
    for (int j = 0; j < 4; ++j) acc[i][j] = fzero;

  STAGE_A(p0, 0); STAGE_B(p0, 0);
  STAGE_A(p1, 1); STAGE_B(p1, 1);
  asm volatile("s_waitcnt vmcnt(4)" ::: "memory");
  __builtin_amdgcn_sched_barrier(0);
  __builtin_amdgcn_s_barrier();
  __builtin_amdgcn_sched_barrier(0);

  for (int kt = 0; kt < NT; ++kt) {
    const bool doStage = (kt < NT - 2);
    if (doStage) STAGE_A(p2, kt + 2);
    bf16x8 bfr[4], afr[4];
#pragma unroll
    for (int j = 0; j < 4; ++j) bfr[j] = *(const bf16x8*)(p0 + bOff + j * 1024);
#pragma unroll
    for (int i = 0; i < 4; ++i) afr[i] = *(const bf16x8*)(p0 + aOff + i * 1024);
    __builtin_amdgcn_s_setprio(1);
#pragma unroll
    for (int i = 0; i < 4; ++i)
#pragma unroll
      for (int j = 0; j < 4; ++j) acc[i][j] = MFMA_16x16x32(afr[i], bfr[j], acc[i][j]);
    __builtin_amdgcn_s_setprio(0);
    if (doStage) STAGE_B(p2, kt + 2);
#pragma unroll
    for (int i = 0; i < 4; ++i) afr[i] = *(const bf16x8*)(p0 + aOff + (4 + i) * 1024);
    __builtin_amdgcn_s_setprio(1);
#pragma unroll
    for (int i = 0; i < 4; ++i)
#pragma unroll
      for (int j = 0; j < 4; ++j) acc[4 + i][j] = MFMA_16x16x32(afr[i], bfr[j], acc[4 + i][j]);
    __builtin_amdgcn_s_setprio(0);
    if (doStage) {
      asm volatile("s_waitcnt vmcnt(4) lgkmcnt(0)" ::: "memory");
    } else {
      asm volatile("s_waitcnt vmcnt(0) lgkmcnt(0)" ::: "memory");
    }
    __builtin_amdgcn_sched_barrier(0);
    __builtin_amdgcn_s_barrier();
    __builtin_amdgcn_sched_barrier(0);
    char* t = p0; p0 = p1; p1 = p2; p2 = t;
  }
#undef STAGE_A
#undef STAGE_B

  // fp32 coalesced epilogue: col contiguous across l15 (64B/group).
#pragma unroll
  for (int j = 0; j < 4; ++j) {
    const int col = bcol + wc * 64 + j * 16 + l15;
    const float bb = bias[col];
#pragma unroll
    for (int i = 0; i < 8; ++i) {
#pragma unroll
      for (int r = 0; r < 4; ++r) {
        const int row = brow + wr * 128 + i * 16 + g * 4 + r;
        Cout[(size_t)row * 2048 + col] = acc[i][j][r] + bb;
      }
    }
  }
}

// ---------------------------------------------------------------- flash attention
// Now launched twice (512 blocks each, bh0 = 0 / 16) for rocprof attribution.
__global__ __launch_bounds__(256) void attn_kernel(const ushort_t* __restrict__ Q,
                                                   const ushort_t* __restrict__ K,
                                                   const ushort_t* __restrict__ Vt,
                                                   ushort_t* __restrict__ O, int bh0) {
  constexpr int S = 2048, D = 128, H = 16;
  __shared__ __align__(16) char smem[16384 + 16384 + 9216];
  char* sK = smem;
  char* sVt = smem + 16384;
  char* sP = smem + 32768;

  const int tid = threadIdx.x;
  const int wave = tid >> 6;
  const int lane = tid & 63;
  const int g = lane >> 4;
  const int l15 = lane & 15;
  const int qt = blockIdx.x & 31;
  const int bh = bh0 + (blockIdx.x >> 5);
  const int b = bh >> 4, h = bh & 15;

  const ushort_t* Qb = Q + (size_t)bh * S * D;
  const char* Kb = (const char*)(K + (size_t)bh * S * D);
  const char* Vtb = (const char*)(Vt + (size_t)bh * D * S);
  const int q0 = qt * 64 + wave * 16;

  bf16x8 aq[4];
  {
    const ushort_t* qrow = Qb + (size_t)(q0 + l15) * D + g * 8;
#pragma unroll
    for (int kk = 0; kk < 4; ++kk) aq[kk] = *(const bf16x8*)(qrow + kk * 32);
  }

  const char* kg[4];
  const char* vg[4];
#pragma unroll
  for (int i = 0; i < 4; ++i) {
    const int po = (wave * 4 + i) * 1024 + lane * 16;
    const int lk = po ^ (((po >> 8) & 7) << 4);
    kg[i] = Kb + (size_t)(lk >> 8) * 256 + (lk & 255);
    const int lv = po ^ (((po >> 7) & 7) << 4);
    vg[i] = Vtb + (size_t)(lv >> 7) * 4096 + (lv & 127);
  }

  const f32x4 fzero = {0.f, 0.f, 0.f, 0.f};
  f32x4 o[8];
#pragma unroll
  for (int nt = 0; nt < 8; ++nt) o[nt] = fzero;
  float row_m[4] = {-1e30f, -1e30f, -1e30f, -1e30f};
  float row_l[4] = {0.f, 0.f, 0.f, 0.f};

  bf16x8 ones;
#pragma unroll
  for (int i = 0; i < 8; ++i) ones[i] = (short)0x3F80;

  char* sPw = sP + wave * 2304;
  const float SC = 0.12751746f;   // (1/sqrt(128))*log2(e)
  const float THR = 90.0f;        // defer-max threshold, raw units

  for (int kv0 = 0; kv0 < S; kv0 += 64) {
    __syncthreads();
#pragma unroll
    for (int i = 0; i < 4; ++i)
      gload_lds16(kg[i] + (size_t)kv0 * 256, sK + (wave * 4 + i) * 1024);
#pragma unroll
    for (int i = 0; i < 4; ++i)
      gload_lds16(vg[i] + (size_t)kv0 * 2, sVt + (wave * 4 + i) * 1024);
    __syncthreads();

    f32x4 sfrag[4];
#pragma unroll
    for (int nt = 0; nt < 4; ++nt) {
      sfrag[nt] = fzero;
#pragma unroll
      for (int kk = 0; kk < 4; ++kk) {
        const int row = nt * 16 + l15;
        const int la = row * 256 + kk * 64 + g * 16;
        const bf16x8 bk = *(const bf16x8*)(sK + (la ^ ((row & 7) << 4)));
        sfrag[nt] = MFMA_16x16x32(aq[kk], bk, sfrag[nt]);
      }
    }

#pragma unroll
    for (int r = 0; r < 4; ++r) {
      const float s0 = sfrag[0][r];
      const float s1 = sfrag[1][r];
      const float s2 = sfrag[2][r];
      const float s3 = sfrag[3][r];
      const float lm = fmaxf(fmaxf(s0, s1), fmaxf(s2, s3));
      if (!__all(lm - row_m[r] <= THR)) {   // wave-uniform branch
        float mx = lm;
        mx = fmaxf(mx, __shfl_xor(mx, 1));
        mx = fmaxf(mx, __shfl_xor(mx, 2));
        mx = fmaxf(mx, __shfl_xor(mx, 4));
        mx = fmaxf(mx, __shfl_xor(mx, 8));
        const float nm = fmaxf(row_m[r], mx);
        const float corr = exp2f((row_m[r] - nm) * SC);
        row_l[r] *= corr;
#pragma unroll
        for (int nt = 0; nt < 8; ++nt) o[nt][r] *= corr;
        row_m[r] = nm;
      }
      const float nm = row_m[r];
      const float p0 = exp2f((s0 - nm) * SC);
      const float p1 = exp2f((s1 - nm) * SC);
      const float p2 = exp2f((s2 - nm) * SC);
      const float p3 = exp2f((s3 - nm) * SC);
      unsigned int pk01, pk23;
      asm("v_cvt_pk_bf16_f32 %0, %1, %2" : "=v"(pk01) : "v"(p0), "v"(p1));
      asm("v_cvt_pk_bf16_f32 %0, %1, %2" : "=v"(pk23) : "v"(p2), "v"(p3));
      ushort_t* pr = (ushort_t*)(sPw + (g * 4 + r) * 144);
      pr[l15] = (ushort_t)(pk01 & 0xffffu);
      pr[16 + l15] = (ushort_t)(pk01 >> 16);
      pr[32 + l15] = (ushort_t)(pk23 & 0xffffu);
      pr[48 + l15] = (ushort_t)(pk23 >> 16);
    }

    const bf16x8 pa0 = *(const bf16x8*)(sPw + l15 * 144 + g * 16);
    const bf16x8 pa1 = *(const bf16x8*)(sPw + l15 * 144 + 64 + g * 16);
    f32x4 lfrag = fzero;
    lfrag = MFMA_16x16x32(pa0, ones, lfrag);
    lfrag = MFMA_16x16x32(pa1, ones, lfrag);
#pragma unroll
    for (int nt = 0; nt < 8; ++nt) {
      const int d = nt * 16 + l15;
      const int la0 = d * 128 + g * 16;
      const bf16x8 bv0 = *(const bf16x8*)(sVt + (la0 ^ ((d & 7) << 4)));
      o[nt] = MFMA_16x16x32(pa0, bv0, o[nt]);
      const bf16x8 bv1 = *(const bf16x8*)(sVt + ((la0 + 64) ^ ((d & 7) << 4)));
      o[nt] = MFMA_16x16x32(pa1, bv1, o[nt]);
    }
#pragma unroll
    for (int r = 0; r < 4; ++r) row_l[r] += lfrag[r];
  }

#pragma unroll
  for (int r = 0; r < 4; ++r) {
    const float inv = 1.0f / row_l[r];
    const int srow = q0 + g * 4 + r;
    ushort_t* orow = O + ((size_t)b * S + srow) * (H * D) + h * D;
#pragma unroll
    for (int nt = 0; nt < 8; ++nt) orow[nt * 16 + l15] = f2bf(o[nt][r] * inv);
  }
}

// ---------------------------------------------------------------- launch
extern "C" void kernel_launch(void* const* d_in, const int* in_sizes, int n_in,
                              void* d_out, int out_size, void* d_ws, size_t ws_size,
                              hipStream_t stream) {
  const float* hidden = (const float*)d_in[0];
  const float* Wq = (const float*)d_in[1];
  const float* bq = (const float*)d_in[2];
  const float* Wk = (const float*)d_in[3];
  const float* bk = (const float*)d_in[4];
  const float* Wv = (const float*)d_in[5];
  const float* bv = (const float*)d_in[6];
  const float* Wo = (const float*)d_in[7];
  const float* bo = (const float*)d_in[8];

  constexpr int M = 4096, N = 2048, Kd = 2048;  // M = B*S
  char* ws = (char*)d_ws;
  // ws: hb 16M | wqkv 24M (wq|wk|wv) | wo 8M | Q 16M | K 16M | Vt 16M | AO 16M = 112M
  ushort_t* hb   = (ushort_t*)(ws);
  ushort_t* wqkv = (ushort_t*)(ws + (16u << 20));
  ushort_t* wob  = (ushort_t*)(ws + (40u << 20));
  ushort_t* Qs   = (ushort_t*)(ws + (48u << 20));
  ushort_t* Ks   = Qs + (size_t)M * N;
  ushort_t* Vts  = Ks + (size_t)M * N;
  ushort_t* AO   = Vts + (size_t)M * N;

  f2bf_kernel<<<2048, 256, 0, stream>>>(hidden, hb, M * Kd / 4);
  f2bfw_kernel<<<2048, 256, 0, stream>>>(Wq, Wk, Wv, Wo, wqkv,
                                         wqkv + (size_t)N * Kd,
                                         wqkv + 2 * (size_t)N * Kd, wob);

  // Q/K: 16 N-blocks x 16 M-blocks = 256 blocks (exactly 1 round @ 1 blk/CU).
  qkv_gemm<0><<<256, 512, 98304, stream>>>(hb, wqkv, bq, bk, bv, Qs, Ks, Vts, 16, 0);
  // V (operand-swapped, coalesced Vt): 8 x 16 = 128 blocks.
  qkv_gemm<1><<<128, 512, 98304, stream>>>(hb, wqkv, bq, bk, bv, Qs, Ks, Vts, 8, 4096);
  // attn split for rocprof attribution: 2 x 512 blocks.
  attn_kernel<<<512, 256, 0, stream>>>(Qs, Ks, Vts, AO, 0);
  attn_kernel<<<512, 256, 0, stream>>>(Qs, Ks, Vts, AO, 16);
  oproj_gemm<<<128, 512, 98304, stream>>>(AO, wob, bo, (float*)d_out);
}